// Round 17
// baseline (145.622 us; speedup 1.0000x reference)
//
#include <hip/hip_runtime.h>
#include <math.h>

#define NJ 16
#define NV 778
#define M3 2334   // NV*3
#define S  8      // samples per group in k3a

typedef float f32x8 __attribute__((ext_vector_type(8)));

__device__ __forceinline__ f32x8 splat8(float x) {
    f32x8 r;
#pragma unroll
    for (int i = 0; i < 8; ++i) r[i] = x;
    return r;
}

// d_out layout (floats): verts [N*2334] | joints [N*48] | Rs [N*144]
// d_ws layout (floats):  A [N*192] | Fg/jpart [N*192] (time-shared: k2b writes
//   Fg (2.32 MB), k3a reads it, then k4b overwrites the region as jpart)
// Pipeline: k0 -> k1 -> k2(A->ws) -> k2b(F->ws) -> k3a(v_posed->verts, features
//   via SGPR s_load) -> k4a(blend, A in LDS) -> k4b(joint partials) -> k5
//
// LAUNCH-BOUNDS LESSON (R4, R8): second arg w caps VGPR at 256/w -> only (B,1).
// LATENCY LESSONS (R9-R16): (a) per-sample multi-barrier blocks serialize;
// (b) dependent L2 chains need LDS staging (k4a); (c) wave-uniform operands
// through LDS serialize the per-CU LDS unit -- use scalar pipe (s_load+SGPR
// v_fmac); (d) TLP matters: 4 waves/SIMD leaves ~50% VALU idle at this
// load:FMA ratio -- size the grid for 8 waves/SIMD when VGPR<=64.

// ---------------- K0: SJ[b,j,c] = sum_v shapedirs[b,v,c]*Jreg[v,j]; b==10 -> vtemp
__global__ __launch_bounds__(64) void k0_prep(
    const float* __restrict__ shapedirs,
    const float* __restrict__ Jreg,
    const float* __restrict__ vtemp,
    float* __restrict__ SJJT)   // 528 floats
{
    int b = blockIdx.x / 16;    // 0..9 = shapedirs row, 10 = vtemp
    int j = blockIdx.x % 16;
    int t = threadIdx.x;
    const float* src = (b < 10) ? (shapedirs + (size_t)b * M3) : vtemp;
    float a0 = 0.f, a1 = 0.f, a2 = 0.f;
    for (int v = t; v < NV; v += 64) {
        float jr = Jreg[v * 16 + j];
        a0 = fmaf(src[v*3 + 0], jr, a0);
        a1 = fmaf(src[v*3 + 1], jr, a1);
        a2 = fmaf(src[v*3 + 2], jr, a2);
    }
#pragma unroll
    for (int m = 1; m < 64; m <<= 1) {
        a0 += __shfl_xor(a0, m);
        a1 += __shfl_xor(a1, m);
        a2 += __shfl_xor(a2, m);
    }
    if (t == 0) {
        int base = (b < 10) ? (b*48 + j*3) : (480 + j*3);
        SJJT[base + 0] = a0;
        SJJT[base + 1] = a1;
        SJJT[base + 2] = a2;
    }
}

// ---------------- K1: Rodrigues, one thread per (n, joint)
__global__ __launch_bounds__(256) void k1_rodrigues(
    const float* __restrict__ theta, float* __restrict__ RsOut, int N)
{
    int idx = blockIdx.x * 256 + threadIdx.x;
    if (idx >= N * NJ) return;
    int n = idx >> 4;
    int j = idx & 15;
    float t0 = theta[n*48 + j*3 + 0];
    float t1 = theta[n*48 + j*3 + 1];
    float t2 = theta[n*48 + j*3 + 2];
    const float eps = 1e-8f;
    float a0 = t0 + eps, a1 = t1 + eps, a2 = t2 + eps;
    float angle = sqrtf(a0*a0 + a1*a1 + a2*a2);
    float inv  = 1.0f / angle;
    float half = 0.5f * angle;
    float sh = sinf(half), chh = cosf(half);
    float qw = chh;
    float qx = sh * t0 * inv;
    float qy = sh * t1 * inv;
    float qz = sh * t2 * inv;
    float qn = 1.0f / sqrtf(qw*qw + qx*qx + qy*qy + qz*qz);
    qw *= qn; qx *= qn; qy *= qn; qz *= qn;
    float w2=qw*qw, x2=qx*qx, y2=qy*qy, z2=qz*qz;
    float wx=qw*qx, wy=qw*qy, wz=qw*qz;
    float xy=qx*qy, xz=qx*qz, yz=qy*qz;
    float* R = RsOut + (size_t)idx * 9;
    R[0] = w2 + x2 - y2 - z2;
    R[1] = 2.f*(xy - wz);
    R[2] = 2.f*(wy + xz);
    R[3] = 2.f*(wz + xy);
    R[4] = w2 - x2 + y2 - z2;
    R[5] = 2.f*(yz - wx);
    R[6] = 2.f*(xz - wy);
    R[7] = 2.f*(wx + yz);
    R[8] = w2 - x2 - y2 + z2;
}

// ---------------- K2: kinematic chain -> A into d_ws (192 floats / sample)
__global__ __launch_bounds__(64) void k2_chain(
    const float* __restrict__ beta,
    const float* __restrict__ Rs,     // d_out Rs region
    const float* __restrict__ SJJT,   // 528 floats
    float* __restrict__ Aws,          // d_ws; A[n] at n*192
    int N)
{
    __shared__ float sS[528];
    for (int i = threadIdx.x; i < 528; i += 64) sS[i] = SJJT[i];
    __syncthreads();
    int gid = blockIdx.x * 64 + threadIdx.x;
    if (gid >= N * 5) return;
    int n  = gid / 5;
    int ch = gid % 5;

    float b[10];
#pragma unroll
    for (int i = 0; i < 10; ++i) b[i] = beta[n*10 + i];

    int jidx[4];
    jidx[0] = 0; jidx[1] = ch*3 + 1; jidx[2] = ch*3 + 2; jidx[3] = ch*3 + 3;
    float J[4][3];
#pragma unroll
    for (int q = 0; q < 4; ++q) {
        int j = jidx[q];
#pragma unroll
        for (int c = 0; c < 3; ++c) {
            float acc = sS[480 + j*3 + c];
#pragma unroll
            for (int qq = 0; qq < 10; ++qq)
                acc = fmaf(b[qq], sS[qq*48 + j*3 + c], acc);
            J[q][c] = acc;
        }
    }

    const float* Rn = Rs + (size_t)n * 144;
    float* An = Aws + (size_t)n * 192;

    float GpR[9], Gpt[3];
#pragma unroll
    for (int r = 0; r < 3; ++r) {
        GpR[r*3+0] =  Rn[r*3+0];
        GpR[r*3+1] = -Rn[r*3+1];
        GpR[r*3+2] = -Rn[r*3+2];
    }
    Gpt[0] = J[0][0]; Gpt[1] = J[0][1]; Gpt[2] = J[0][2];

    if (ch == 0) {
#pragma unroll
        for (int r = 0; r < 3; ++r) {
            float rel = GpR[r*3+0]*J[0][0] + GpR[r*3+1]*J[0][1] + GpR[r*3+2]*J[0][2];
            An[r*4 + 0] = GpR[r*3+0];
            An[r*4 + 1] = GpR[r*3+1];
            An[r*4 + 2] = GpR[r*3+2];
            An[r*4 + 3] = Gpt[r] - rel;
        }
    }

#pragma unroll
    for (int st = 0; st < 3; ++st) {
        int i = jidx[st+1];
        const float* Ri = Rn + (size_t)i * 9;
        float t0 = J[st+1][0] - J[st][0];
        float t1 = J[st+1][1] - J[st][1];
        float t2 = J[st+1][2] - J[st][2];
        float GR[9], Gt[3];
#pragma unroll
        for (int r = 0; r < 3; ++r) {
#pragma unroll
            for (int c = 0; c < 3; ++c)
                GR[r*3+c] = GpR[r*3+0]*Ri[c] + GpR[r*3+1]*Ri[3+c] + GpR[r*3+2]*Ri[6+c];
            Gt[r] = GpR[r*3+0]*t0 + GpR[r*3+1]*t1 + GpR[r*3+2]*t2 + Gpt[r];
        }
#pragma unroll
        for (int r = 0; r < 3; ++r) {
            float rel = GR[r*3+0]*J[st+1][0] + GR[r*3+1]*J[st+1][1] + GR[r*3+2]*J[st+1][2];
            An[i*12 + r*4 + 0] = GR[r*3+0];
            An[i*12 + r*4 + 1] = GR[r*3+1];
            An[i*12 + r*4 + 2] = GR[r*3+2];
            An[i*12 + r*4 + 3] = Gt[r] - rel;
        }
#pragma unroll
        for (int r = 0; r < 9; ++r) GpR[r] = GR[r];
        Gpt[0] = Gt[0]; Gpt[1] = Gt[1]; Gpt[2] = Gt[2];
    }
}

// ---------------- K2b: features -> global Fg[g][k][8] (g = sample group of 8)
__global__ __launch_bounds__(256) void k2b_feat(
    const float* __restrict__ beta,
    const float* __restrict__ Rs,
    float* __restrict__ Fg,             // [N/8][145][8]
    int N)
{
    int idx = blockIdx.x * 256 + threadIdx.x;   // total (N/8)*145*8
    int total = (N / 8) * 145 * 8;
    if (idx >= total) return;
    int s = idx & 7;
    int k = (idx >> 3) % 145;
    int g = idx / (145 * 8);
    int n = g * 8 + s;
    float val;
    if (k < 10) {
        val = beta[(size_t)n * 10 + k];
    } else {
        int kk = k - 10;
        int rr = kk % 9;
        val = Rs[(size_t)n * 144 + 9 + kk];
        if ((rr & 3) == 0) val -= 1.f;          // rr in {0,4,8}
    }
    Fg[idx] = val;
}

// ---------------- K3a: GEMM, features via SCALAR pipe. Block = 8 samples x
// 256-vert quarter; 1 vert/thread, acc = 3 f32x8 = 24 VGPR (~40 total) ->
// 8 waves/SIMD resident with grid (N/8, 4) = 2048 blocks = 32 waves/CU.
#define FROW8(FP, X_, Y_, Z_) { \
    float F0=(FP)[0], F1=(FP)[1], F2=(FP)[2], F3=(FP)[3]; \
    float F4=(FP)[4], F5=(FP)[5], F6=(FP)[6], F7=(FP)[7]; \
    ax[0]=fmaf(F0,X_,ax[0]); ay[0]=fmaf(F0,Y_,ay[0]); az[0]=fmaf(F0,Z_,az[0]); \
    ax[1]=fmaf(F1,X_,ax[1]); ay[1]=fmaf(F1,Y_,ay[1]); az[1]=fmaf(F1,Z_,az[1]); \
    ax[2]=fmaf(F2,X_,ax[2]); ay[2]=fmaf(F2,Y_,ay[2]); az[2]=fmaf(F2,Z_,az[2]); \
    ax[3]=fmaf(F3,X_,ax[3]); ay[3]=fmaf(F3,Y_,ay[3]); az[3]=fmaf(F3,Z_,az[3]); \
    ax[4]=fmaf(F4,X_,ax[4]); ay[4]=fmaf(F4,Y_,ay[4]); az[4]=fmaf(F4,Z_,az[4]); \
    ax[5]=fmaf(F5,X_,ax[5]); ay[5]=fmaf(F5,Y_,ay[5]); az[5]=fmaf(F5,Z_,az[5]); \
    ax[6]=fmaf(F6,X_,ax[6]); ay[6]=fmaf(F6,Y_,ay[6]); az[6]=fmaf(F6,Z_,az[6]); \
    ax[7]=fmaf(F7,X_,ax[7]); ay[7]=fmaf(F7,Y_,ay[7]); az[7]=fmaf(F7,Z_,az[7]); }

__global__ __launch_bounds__(256, 1) void k3a_gemm(
    const float* __restrict__ Fg,       // [N/8][145][8] (ws, from k2b)
    const float* __restrict__ posedirs,
    const float* __restrict__ shapedirs,
    const float* __restrict__ vtemp,
    float* __restrict__ vposed,         // verts region
    int N)
{
    const int g   = blockIdx.x;                 // sample group
    const int n0  = g * S;
    const int tid = threadIdx.x;
    const int v   = blockIdx.y * 256 + tid;     // 0..1023
    const int vc  = (v < NV) ? v : (NV - 1);    // clamp: no divergence

    const float* F = Fg + (size_t)g * 145 * 8;  // uniform base

    f32x8 ax = splat8(vtemp[vc*3+0]);
    f32x8 ay = splat8(vtemp[vc*3+1]);
    f32x8 az = splat8(vtemp[vc*3+2]);

    // shapedirs rows 0..9
#pragma unroll
    for (int k = 0; k < 10; ++k) {
        const float* r_ = shapedirs + (size_t)k*M3 + 3*vc;
        float x_ = r_[0], y_ = r_[1], z_ = r_[2];
        FROW8(F + k*8, x_, y_, z_)
    }

    // posedirs rows 10..144, depth-2 prefetch on the per-lane vector load
    {
        const float* r0_ = posedirs + 3*vc;
        const float* r1_ = posedirs + (size_t)1*M3 + 3*vc;
        float x0 = r0_[0], y0 = r0_[1], z0 = r0_[2];
        float x1 = r1_[0], y1 = r1_[1], z1 = r1_[2];
        for (int k = 0; k < 135; ++k) {
            int kn = (k + 2 < 135) ? (k + 2) : 134;
            const float* rn_ = posedirs + (size_t)kn*M3 + 3*vc;
            float nx = rn_[0], ny = rn_[1], nz = rn_[2];
            FROW8(F + (k + 10)*8, x0, y0, z0)
            x0 = x1; y0 = y1; z0 = z1;
            x1 = nx; y1 = ny; z1 = nz;
        }
    }

#pragma unroll
    for (int s = 0; s < S; ++s) {
        float* o = vposed + (size_t)(n0 + s)*M3 + (size_t)vc*3;
        o[0] = ax[s]; o[1] = ay[s]; o[2] = az[s];
    }
}

// ---------------- K4a: LBS blend, A staged in LDS. grid (N, 2); 2 verts/thread.
__global__ __launch_bounds__(256, 1) void k4a_blend(
    const float* __restrict__ Aws,      // d_ws
    const float* __restrict__ weights,
    float* verts,                       // in-place
    int N)
{
    typedef float f32x16v __attribute__((ext_vector_type(16)));
    __shared__ __attribute__((aligned(16))) float4 sA4[48];
    const int n   = blockIdx.x;
    const int q   = blockIdx.y;
    const int tid = threadIdx.x;

    if (tid < 48) sA4[tid] = reinterpret_cast<const float4*>(Aws + (size_t)n * 192)[tid];

    const int v0 = q * 512 + tid;               // always < 778
    const int v1 = v0 + 256;                    // q=1: 768..1023 -> guard
    const bool m1 = v1 < NV;
    const int c1 = m1 ? v1 : (NV - 1);

    float* vp0 = verts + (size_t)n * M3 + (size_t)v0 * 3;
    float* vp1 = verts + (size_t)n * M3 + (size_t)c1 * 3;
    float x0 = vp0[0], y0 = vp0[1], z0 = vp0[2];
    float x1 = vp1[0], y1 = vp1[1], z1 = vp1[2];
    f32x16v w0 = *reinterpret_cast<const f32x16v*>(&weights[(size_t)v0 * 16]);
    f32x16v w1 = *reinterpret_cast<const f32x16v*>(&weights[(size_t)c1 * 16]);

    __syncthreads();   // sA4 ready

    float o0x=0.f,o0y=0.f,o0z=0.f, o1x=0.f,o1y=0.f,o1z=0.f;

#define BJA2(j_) { \
    float4 A0 = sA4[(j_)*3+0], A1 = sA4[(j_)*3+1], A2 = sA4[(j_)*3+2]; \
    float X,Y,Z; \
    X = fmaf(A0.x,x0, fmaf(A0.y,y0, fmaf(A0.z,z0, A0.w))); \
    Y = fmaf(A1.x,x0, fmaf(A1.y,y0, fmaf(A1.z,z0, A1.w))); \
    Z = fmaf(A2.x,x0, fmaf(A2.y,y0, fmaf(A2.z,z0, A2.w))); \
    o0x = fmaf(w0[j_], X, o0x); o0y = fmaf(w0[j_], Y, o0y); o0z = fmaf(w0[j_], Z, o0z); \
    X = fmaf(A0.x,x1, fmaf(A0.y,y1, fmaf(A0.z,z1, A0.w))); \
    Y = fmaf(A1.x,x1, fmaf(A1.y,y1, fmaf(A1.z,z1, A1.w))); \
    Z = fmaf(A2.x,x1, fmaf(A2.y,y1, fmaf(A2.z,z1, A2.w))); \
    o1x = fmaf(w1[j_], X, o1x); o1y = fmaf(w1[j_], Y, o1y); o1z = fmaf(w1[j_], Z, o1z); }

    BJA2(0)  BJA2(1)  BJA2(2)  BJA2(3)  BJA2(4)  BJA2(5)  BJA2(6)  BJA2(7)
    BJA2(8)  BJA2(9)  BJA2(10) BJA2(11) BJA2(12) BJA2(13) BJA2(14) BJA2(15)
#undef BJA2

    vp0[0] = o0x; vp0[1] = o0y; vp0[2] = o0z;
    if (m1) { vp1[0] = o1x; vp1[1] = o1y; vp1[2] = o1z; }
}

// ---------------- K4b: joint partials, barrier-free. One thread per
// (n, chunk, j), j fastest (coalesced Jreg; verts broadcast across j-lanes).
__global__ __launch_bounds__(256, 1) void k4b_joints(
    const float* __restrict__ verts,
    const float* __restrict__ Jreg,
    float* __restrict__ jpart,          // d_ws + N*192 (overwrites Fg)
    int N)
{
    int gid = blockIdx.x * 256 + threadIdx.x;   // total N*4*16
    if (gid >= N * 64) return;
    int j  = gid & 15;
    int c4 = (gid >> 4) & 3;
    int n  = gid >> 6;

    int vbeg = c4 * 195;
    int vend = vbeg + 195; if (vend > NV) vend = NV;

    const float* vp = verts + (size_t)n * M3;
    float a0 = 0.f, a1 = 0.f, a2 = 0.f;
#pragma unroll 4
    for (int v = vbeg; v < vend; ++v) {
        float jr = Jreg[(size_t)v * 16 + j];
        float x = vp[v*3 + 0], y = vp[v*3 + 1], z = vp[v*3 + 2];
        a0 = fmaf(jr, x, a0);
        a1 = fmaf(jr, y, a1);
        a2 = fmaf(jr, z, a2);
    }
    float* o = jpart + (size_t)n * 192 + c4 * 48 + j * 3;
    o[0] = a0; o[1] = a1; o[2] = a2;
}

// ---------------- K5: joints[n*48+r] = sum_c4 jpart[n*192 + c4*48 + r]
__global__ __launch_bounds__(256) void k5_joint_sum(
    const float* __restrict__ jpart, float* __restrict__ joints, int N)
{
    int i = blockIdx.x * 256 + threadIdx.x;     // N*48
    if (i >= N * 48) return;
    int n = i / 48;
    int r = i - n * 48;
    const float* p = jpart + (size_t)n * 192 + r;
    joints[i] = p[0] + p[48] + p[96] + p[144];
}

extern "C" void kernel_launch(void* const* d_in, const int* in_sizes, int n_in,
                              void* d_out, int out_size, void* d_ws, size_t ws_size,
                              hipStream_t stream)
{
    const float* beta   = (const float*)d_in[0];
    const float* theta  = (const float*)d_in[1];
    const float* vtemp  = (const float*)d_in[2];
    const float* shaped = (const float*)d_in[3];
    const float* Jreg   = (const float*)d_in[4];
    const float* posed  = (const float*)d_in[5];
    const float* wts    = (const float*)d_in[6];
    float* out = (float*)d_out;
    const int N = in_sizes[0] / 10;   // 4096

    float* verts  = out;                            // N*2334
    float* joints = out + (size_t)N * M3;           // N*48
    float* RsOut  = joints + (size_t)N * 48;        // N*144
    float* Aws    = (float*)d_ws;                   // N*192 floats = 3.1 MB
    float* Fg     = Aws + (size_t)N * 192;          // 2.32 MB (then jpart)
    float* jpart  = Fg;                             // k4b overwrites after k3a

    const int nF = (N / 8) * 145 * 8;

    k0_prep<<<176, 64, 0, stream>>>(shaped, Jreg, vtemp, joints);
    k1_rodrigues<<<(N*NJ + 255)/256, 256, 0, stream>>>(theta, RsOut, N);
    k2_chain<<<(N*5 + 63)/64, 64, 0, stream>>>(beta, RsOut, joints, Aws, N);
    k2b_feat<<<(nF + 255)/256, 256, 0, stream>>>(beta, RsOut, Fg, N);
    k3a_gemm<<<dim3(N/S, 4), 256, 0, stream>>>(Fg, posed, shaped, vtemp, verts, N);
    k4a_blend<<<dim3(N, 2), 256, 0, stream>>>(Aws, wts, verts, N);
    k4b_joints<<<(N*64 + 255)/256, 256, 0, stream>>>(verts, Jreg, jpart, N);
    k5_joint_sum<<<(N*48 + 255)/256, 256, 0, stream>>>(jpart, joints, N);
}

// Round 18
// 113.963 us; speedup vs baseline: 1.2778x; 1.2778x over previous
//
#include <hip/hip_runtime.h>
#include <math.h>

#define NJ 16
#define NV 778
#define M3 2334   // NV*3
#define KP 160    // K padded (10 shape + 135 pose + 15 zero)
#define NTB 148   // padded B n-tiles (2334/16 = 145.875 -> 146, pad to 148)

typedef float f32x4  __attribute__((ext_vector_type(4)));
typedef short bf16x8 __attribute__((ext_vector_type(8)));

__device__ __forceinline__ unsigned short f2bf(float x) {
    unsigned int u = __float_as_uint(x);
    unsigned int r = (u + 0x7FFF + ((u >> 16) & 1)) >> 16;   // RNE
    return (unsigned short)r;
}

// d_out layout (floats): verts [N*2334] | joints [N*48] | Rs [N*144]
// d_ws layout (floats):  A [N*192] | {Afrag 1.31MB | Bfrag 0.74MB} / jpart
//   (time-shared: k2a/k2c write frags, k3a_mfma reads them, then k4b
//    overwrites the same region as jpart [N*192])
// Pipeline: k0 -> k1 -> k2(A->ws) -> k2a/k2c(bf16 MFMA frags) ->
//   k3a_mfma(C=F@D + vtemp -> verts) -> k4a(blend, A in LDS) -> k4b -> k5
//
// LAUNCH-BOUNDS LESSON (R4,R8): second arg w caps VGPR at 256/w -> only (B,1).
// LATENCY LESSONS (R9-R17): (a) multi-barrier per-sample blocks serialize;
// (b) dependent L2 chains -> LDS staging; (c) wave-uniform operands -> scalar
// pipe; (d) VALU GEMM plateaus at ~2x issue floor; matmul-shaped work with
// K>=16 belongs on MFMA (Guideline 10).

// ---------------- K0: SJ[b,j,c] = sum_v shapedirs[b,v,c]*Jreg[v,j]; b==10 -> vtemp
__global__ __launch_bounds__(64) void k0_prep(
    const float* __restrict__ shapedirs,
    const float* __restrict__ Jreg,
    const float* __restrict__ vtemp,
    float* __restrict__ SJJT)   // 528 floats
{
    int b = blockIdx.x / 16;    // 0..9 = shapedirs row, 10 = vtemp
    int j = blockIdx.x % 16;
    int t = threadIdx.x;
    const float* src = (b < 10) ? (shapedirs + (size_t)b * M3) : vtemp;
    float a0 = 0.f, a1 = 0.f, a2 = 0.f;
    for (int v = t; v < NV; v += 64) {
        float jr = Jreg[v * 16 + j];
        a0 = fmaf(src[v*3 + 0], jr, a0);
        a1 = fmaf(src[v*3 + 1], jr, a1);
        a2 = fmaf(src[v*3 + 2], jr, a2);
    }
#pragma unroll
    for (int m = 1; m < 64; m <<= 1) {
        a0 += __shfl_xor(a0, m);
        a1 += __shfl_xor(a1, m);
        a2 += __shfl_xor(a2, m);
    }
    if (t == 0) {
        int base = (b < 10) ? (b*48 + j*3) : (480 + j*3);
        SJJT[base + 0] = a0;
        SJJT[base + 1] = a1;
        SJJT[base + 2] = a2;
    }
}

// ---------------- K1: Rodrigues, one thread per (n, joint)
__global__ __launch_bounds__(256) void k1_rodrigues(
    const float* __restrict__ theta, float* __restrict__ RsOut, int N)
{
    int idx = blockIdx.x * 256 + threadIdx.x;
    if (idx >= N * NJ) return;
    int n = idx >> 4;
    int j = idx & 15;
    float t0 = theta[n*48 + j*3 + 0];
    float t1 = theta[n*48 + j*3 + 1];
    float t2 = theta[n*48 + j*3 + 2];
    const float eps = 1e-8f;
    float a0 = t0 + eps, a1 = t1 + eps, a2 = t2 + eps;
    float angle = sqrtf(a0*a0 + a1*a1 + a2*a2);
    float inv  = 1.0f / angle;
    float half = 0.5f * angle;
    float sh = sinf(half), chh = cosf(half);
    float qw = chh;
    float qx = sh * t0 * inv;
    float qy = sh * t1 * inv;
    float qz = sh * t2 * inv;
    float qn = 1.0f / sqrtf(qw*qw + qx*qx + qy*qy + qz*qz);
    qw *= qn; qx *= qn; qy *= qn; qz *= qn;
    float w2=qw*qw, x2=qx*qx, y2=qy*qy, z2=qz*qz;
    float wx=qw*qx, wy=qw*qy, wz=qw*qz;
    float xy=qx*qy, xz=qx*qz, yz=qy*qz;
    float* R = RsOut + (size_t)idx * 9;
    R[0] = w2 + x2 - y2 - z2;
    R[1] = 2.f*(xy - wz);
    R[2] = 2.f*(wy + xz);
    R[3] = 2.f*(wz + xy);
    R[4] = w2 - x2 + y2 - z2;
    R[5] = 2.f*(yz - wx);
    R[6] = 2.f*(xz - wy);
    R[7] = 2.f*(wx + yz);
    R[8] = w2 - x2 - y2 + z2;
}

// ---------------- K2: kinematic chain -> A into d_ws (192 floats / sample)
__global__ __launch_bounds__(64) void k2_chain(
    const float* __restrict__ beta,
    const float* __restrict__ Rs,     // d_out Rs region
    const float* __restrict__ SJJT,   // 528 floats
    float* __restrict__ Aws,          // d_ws; A[n] at n*192
    int N)
{
    __shared__ float sS[528];
    for (int i = threadIdx.x; i < 528; i += 64) sS[i] = SJJT[i];
    __syncthreads();
    int gid = blockIdx.x * 64 + threadIdx.x;
    if (gid >= N * 5) return;
    int n  = gid / 5;
    int ch = gid % 5;

    float b[10];
#pragma unroll
    for (int i = 0; i < 10; ++i) b[i] = beta[n*10 + i];

    int jidx[4];
    jidx[0] = 0; jidx[1] = ch*3 + 1; jidx[2] = ch*3 + 2; jidx[3] = ch*3 + 3;
    float J[4][3];
#pragma unroll
    for (int q = 0; q < 4; ++q) {
        int j = jidx[q];
#pragma unroll
        for (int c = 0; c < 3; ++c) {
            float acc = sS[480 + j*3 + c];
#pragma unroll
            for (int qq = 0; qq < 10; ++qq)
                acc = fmaf(b[qq], sS[qq*48 + j*3 + c], acc);
            J[q][c] = acc;
        }
    }

    const float* Rn = Rs + (size_t)n * 144;
    float* An = Aws + (size_t)n * 192;

    float GpR[9], Gpt[3];
#pragma unroll
    for (int r = 0; r < 3; ++r) {
        GpR[r*3+0] =  Rn[r*3+0];
        GpR[r*3+1] = -Rn[r*3+1];
        GpR[r*3+2] = -Rn[r*3+2];
    }
    Gpt[0] = J[0][0]; Gpt[1] = J[0][1]; Gpt[2] = J[0][2];

    if (ch == 0) {
#pragma unroll
        for (int r = 0; r < 3; ++r) {
            float rel = GpR[r*3+0]*J[0][0] + GpR[r*3+1]*J[0][1] + GpR[r*3+2]*J[0][2];
            An[r*4 + 0] = GpR[r*3+0];
            An[r*4 + 1] = GpR[r*3+1];
            An[r*4 + 2] = GpR[r*3+2];
            An[r*4 + 3] = Gpt[r] - rel;
        }
    }

#pragma unroll
    for (int st = 0; st < 3; ++st) {
        int i = jidx[st+1];
        const float* Ri = Rn + (size_t)i * 9;
        float t0 = J[st+1][0] - J[st][0];
        float t1 = J[st+1][1] - J[st][1];
        float t2 = J[st+1][2] - J[st][2];
        float GR[9], Gt[3];
#pragma unroll
        for (int r = 0; r < 3; ++r) {
#pragma unroll
            for (int c = 0; c < 3; ++c)
                GR[r*3+c] = GpR[r*3+0]*Ri[c] + GpR[r*3+1]*Ri[3+c] + GpR[r*3+2]*Ri[6+c];
            Gt[r] = GpR[r*3+0]*t0 + GpR[r*3+1]*t1 + GpR[r*3+2]*t2 + Gpt[r];
        }
#pragma unroll
        for (int r = 0; r < 3; ++r) {
            float rel = GR[r*3+0]*J[st+1][0] + GR[r*3+1]*J[st+1][1] + GR[r*3+2]*J[st+1][2];
            An[i*12 + r*4 + 0] = GR[r*3+0];
            An[i*12 + r*4 + 1] = GR[r*3+1];
            An[i*12 + r*4 + 2] = GR[r*3+2];
            An[i*12 + r*4 + 3] = Gt[r] - rel;
        }
#pragma unroll
        for (int r = 0; r < 9; ++r) GpR[r] = GR[r];
        Gpt[0] = Gt[0]; Gpt[1] = Gt[1]; Gpt[2] = Gt[2];
    }
}

// ---------------- K2a: A-operand MFMA fragments, bf16.
// A[m=n][k] : k<10 -> beta; 10<=k<145 -> Rs-I; else 0.
// Frag layout (16x16x32): lane holds A[row=lane&15][k0 = ks*32+(lane>>4)*8 ..+7]
// Afrag index = ((mt*5 + ks)*64 + lane)
__global__ __launch_bounds__(256) void k2a_frag(
    const float* __restrict__ beta,
    const float* __restrict__ Rs,
    bf16x8* __restrict__ Af,
    int N)
{
    int idx = blockIdx.x * 256 + threadIdx.x;   // (N/16)*5*64
    if (idx >= (N / 16) * 5 * 64) return;
    int lane = idx & 63;
    int ks   = (idx >> 6) % 5;
    int mt   = idx / 320;
    int n  = mt * 16 + (lane & 15);
    int k0 = ks * 32 + (lane >> 4) * 8;
    bf16x8 o;
#pragma unroll
    for (int j = 0; j < 8; ++j) {
        int k = k0 + j;
        float val;
        if (k < 10) {
            val = beta[(size_t)n * 10 + k];
        } else if (k < 145) {
            int kk = k - 10;
            int rr = kk % 9;
            val = Rs[(size_t)n * 144 + 9 + kk];
            if ((rr & 3) == 0) val -= 1.f;      // rr in {0,4,8}
        } else {
            val = 0.f;
        }
        o[j] = (short)f2bf(val);
    }
    Af[idx] = o;
}

// ---------------- K2c: B-operand MFMA fragments, bf16.
// B[k][col] : k<10 -> shapedirs[k][col]; 10<=k<145 -> posedirs[k-10][col]; else 0.
// Frag layout: lane holds B[k0..k0+7][col = nt*16 + (lane&15)]
// Bfrag index = ((nt*5 + ks)*64 + lane)
__global__ __launch_bounds__(256) void k2c_frag(
    const float* __restrict__ shapedirs,
    const float* __restrict__ posedirs,
    bf16x8* __restrict__ Bf)
{
    int idx = blockIdx.x * 256 + threadIdx.x;   // NTB*5*64
    if (idx >= NTB * 5 * 64) return;
    int lane = idx & 63;
    int ks   = (idx >> 6) % 5;
    int nt   = idx / 320;
    int col = nt * 16 + (lane & 15);
    int k0  = ks * 32 + (lane >> 4) * 8;
    bf16x8 o;
#pragma unroll
    for (int j = 0; j < 8; ++j) {
        int k = k0 + j;
        float val = 0.f;
        if (col < M3) {
            if (k < 10)       val = shapedirs[(size_t)k * M3 + col];
            else if (k < 145) val = posedirs[(size_t)(k - 10) * M3 + col];
        }
        o[j] = (short)f2bf(val);
    }
    Bf[idx] = o;
}

// ---------------- K3a: MFMA GEMM. One wave computes C tile 16 rows x 64 cols:
// 5 K-steps x 4 n-subtiles of mfma_f32_16x16x32_bf16. All fragment loads are
// 16B/lane coalesced from L2. Epilogue adds vtemp[col], stores fp32 verts.
__global__ __launch_bounds__(256, 1) void k3a_mfma(
    const bf16x8* __restrict__ Af,      // [(N/16)][5][64]
    const bf16x8* __restrict__ Bf,      // [NTB][5][64]
    const float* __restrict__ vtemp,    // 2334 (flattened [v][c] = col order)
    float* __restrict__ verts,
    int N)
{
    const int tid  = threadIdx.x;
    const int w    = tid >> 6;
    const int lane = tid & 63;
    const int mt   = blockIdx.x * 4 + w;        // 0..N/16-1
    const int nt0  = blockIdx.y * 4;            // 0..144 (NTB padded)

    f32x4 acc0 = {0.f,0.f,0.f,0.f};
    f32x4 acc1 = {0.f,0.f,0.f,0.f};
    f32x4 acc2 = {0.f,0.f,0.f,0.f};
    f32x4 acc3 = {0.f,0.f,0.f,0.f};

    const bf16x8* Ab = Af + (size_t)mt * 5 * 64 + lane;
    const bf16x8* Bb = Bf + lane;

#pragma unroll
    for (int ks = 0; ks < 5; ++ks) {
        bf16x8 a  = Ab[ks * 64];
        bf16x8 b0 = Bb[((size_t)(nt0+0) * 5 + ks) * 64];
        bf16x8 b1 = Bb[((size_t)(nt0+1) * 5 + ks) * 64];
        bf16x8 b2 = Bb[((size_t)(nt0+2) * 5 + ks) * 64];
        bf16x8 b3 = Bb[((size_t)(nt0+3) * 5 + ks) * 64];
        acc0 = __builtin_amdgcn_mfma_f32_16x16x32_bf16(a, b0, acc0, 0, 0, 0);
        acc1 = __builtin_amdgcn_mfma_f32_16x16x32_bf16(a, b1, acc1, 0, 0, 0);
        acc2 = __builtin_amdgcn_mfma_f32_16x16x32_bf16(a, b2, acc2, 0, 0, 0);
        acc3 = __builtin_amdgcn_mfma_f32_16x16x32_bf16(a, b3, acc3, 0, 0, 0);
    }

    // C/D layout: col = lane&15, row = (lane>>4)*4 + r  [m89-verified]
    const int row0 = mt * 16 + (lane >> 4) * 4;
    const int cb   = (lane & 15);

#define EPI(accq, q_) { \
    int col = (nt0 + q_) * 16 + cb; \
    if (col < M3) { \
        float vt = vtemp[col]; \
        float* o = verts + (size_t)row0 * M3 + col; \
        o[0]        = accq[0] + vt; \
        o[M3]       = accq[1] + vt; \
        o[2*M3]     = accq[2] + vt; \
        o[3*(size_t)M3] = accq[3] + vt; \
    } }
    EPI(acc0, 0) EPI(acc1, 1) EPI(acc2, 2) EPI(acc3, 3)
#undef EPI
}

// ---------------- K4a: LBS blend, A staged in LDS. grid (N, 2); 2 verts/thread.
__global__ __launch_bounds__(256, 1) void k4a_blend(
    const float* __restrict__ Aws,      // d_ws
    const float* __restrict__ weights,
    float* verts,                       // in-place
    int N)
{
    typedef float f32x16v __attribute__((ext_vector_type(16)));
    __shared__ __attribute__((aligned(16))) float4 sA4[48];
    const int n   = blockIdx.x;
    const int q   = blockIdx.y;
    const int tid = threadIdx.x;

    if (tid < 48) sA4[tid] = reinterpret_cast<const float4*>(Aws + (size_t)n * 192)[tid];

    const int v0 = q * 512 + tid;               // always < 778
    const int v1 = v0 + 256;                    // q=1: 768..1023 -> guard
    const bool m1 = v1 < NV;
    const int c1 = m1 ? v1 : (NV - 1);

    float* vp0 = verts + (size_t)n * M3 + (size_t)v0 * 3;
    float* vp1 = verts + (size_t)n * M3 + (size_t)c1 * 3;
    float x0 = vp0[0], y0 = vp0[1], z0 = vp0[2];
    float x1 = vp1[0], y1 = vp1[1], z1 = vp1[2];
    f32x16v w0 = *reinterpret_cast<const f32x16v*>(&weights[(size_t)v0 * 16]);
    f32x16v w1 = *reinterpret_cast<const f32x16v*>(&weights[(size_t)c1 * 16]);

    __syncthreads();   // sA4 ready

    float o0x=0.f,o0y=0.f,o0z=0.f, o1x=0.f,o1y=0.f,o1z=0.f;

#define BJA2(j_) { \
    float4 A0 = sA4[(j_)*3+0], A1 = sA4[(j_)*3+1], A2 = sA4[(j_)*3+2]; \
    float X,Y,Z; \
    X = fmaf(A0.x,x0, fmaf(A0.y,y0, fmaf(A0.z,z0, A0.w))); \
    Y = fmaf(A1.x,x0, fmaf(A1.y,y0, fmaf(A1.z,z0, A1.w))); \
    Z = fmaf(A2.x,x0, fmaf(A2.y,y0, fmaf(A2.z,z0, A2.w))); \
    o0x = fmaf(w0[j_], X, o0x); o0y = fmaf(w0[j_], Y, o0y); o0z = fmaf(w0[j_], Z, o0z); \
    X = fmaf(A0.x,x1, fmaf(A0.y,y1, fmaf(A0.z,z1, A0.w))); \
    Y = fmaf(A1.x,x1, fmaf(A1.y,y1, fmaf(A1.z,z1, A1.w))); \
    Z = fmaf(A2.x,x1, fmaf(A2.y,y1, fmaf(A2.z,z1, A2.w))); \
    o1x = fmaf(w1[j_], X, o1x); o1y = fmaf(w1[j_], Y, o1y); o1z = fmaf(w1[j_], Z, o1z); }

    BJA2(0)  BJA2(1)  BJA2(2)  BJA2(3)  BJA2(4)  BJA2(5)  BJA2(6)  BJA2(7)
    BJA2(8)  BJA2(9)  BJA2(10) BJA2(11) BJA2(12) BJA2(13) BJA2(14) BJA2(15)
#undef BJA2

    vp0[0] = o0x; vp0[1] = o0y; vp0[2] = o0z;
    if (m1) { vp1[0] = o1x; vp1[1] = o1y; vp1[2] = o1z; }
}

// ---------------- K4b: joint partials, barrier-free. One thread per
// (n, chunk, j), j fastest (coalesced Jreg; verts broadcast across j-lanes).
__global__ __launch_bounds__(256, 1) void k4b_joints(
    const float* __restrict__ verts,
    const float* __restrict__ Jreg,
    float* __restrict__ jpart,          // d_ws + N*192 (overwrites frags)
    int N)
{
    int gid = blockIdx.x * 256 + threadIdx.x;   // total N*4*16
    if (gid >= N * 64) return;
    int j  = gid & 15;
    int c4 = (gid >> 4) & 3;
    int n  = gid >> 6;

    int vbeg = c4 * 195;
    int vend = vbeg + 195; if (vend > NV) vend = NV;

    const float* vp = verts + (size_t)n * M3;
    float a0 = 0.f, a1 = 0.f, a2 = 0.f;
#pragma unroll 4
    for (int v = vbeg; v < vend; ++v) {
        float jr = Jreg[(size_t)v * 16 + j];
        float x = vp[v*3 + 0], y = vp[v*3 + 1], z = vp[v*3 + 2];
        a0 = fmaf(jr, x, a0);
        a1 = fmaf(jr, y, a1);
        a2 = fmaf(jr, z, a2);
    }
    float* o = jpart + (size_t)n * 192 + c4 * 48 + j * 3;
    o[0] = a0; o[1] = a1; o[2] = a2;
}

// ---------------- K5: joints[n*48+r] = sum_c4 jpart[n*192 + c4*48 + r]
__global__ __launch_bounds__(256) void k5_joint_sum(
    const float* __restrict__ jpart, float* __restrict__ joints, int N)
{
    int i = blockIdx.x * 256 + threadIdx.x;     // N*48
    if (i >= N * 48) return;
    int n = i / 48;
    int r = i - n * 48;
    const float* p = jpart + (size_t)n * 192 + r;
    joints[i] = p[0] + p[48] + p[96] + p[144];
}

extern "C" void kernel_launch(void* const* d_in, const int* in_sizes, int n_in,
                              void* d_out, int out_size, void* d_ws, size_t ws_size,
                              hipStream_t stream)
{
    const float* beta   = (const float*)d_in[0];
    const float* theta  = (const float*)d_in[1];
    const float* vtemp  = (const float*)d_in[2];
    const float* shaped = (const float*)d_in[3];
    const float* Jreg   = (const float*)d_in[4];
    const float* posed  = (const float*)d_in[5];
    const float* wts    = (const float*)d_in[6];
    float* out = (float*)d_out;
    const int N = in_sizes[0] / 10;   // 4096

    float* verts  = out;                            // N*2334
    float* joints = out + (size_t)N * M3;           // N*48
    float* RsOut  = joints + (size_t)N * 48;        // N*144
    float* Aws    = (float*)d_ws;                   // N*192 floats = 3.1 MB
    // frag region (aliased with jpart; frags consumed by k3a before k4b writes)
    float*  fbase = Aws + (size_t)N * 192;
    bf16x8* Af    = (bf16x8*)fbase;                          // (N/16)*5*64 *16B
    bf16x8* Bf    = (bf16x8*)(fbase + (size_t)(N/16)*5*64*4);// NTB*5*64 *16B
    float*  jpart = fbase;                                   // k4b overwrites

    const int nA = (N / 16) * 5 * 64;
    const int nB = NTB * 5 * 64;

    k0_prep<<<176, 64, 0, stream>>>(shaped, Jreg, vtemp, joints);
    k1_rodrigues<<<(N*NJ + 255)/256, 256, 0, stream>>>(theta, RsOut, N);
    k2_chain<<<(N*5 + 63)/64, 64, 0, stream>>>(beta, RsOut, joints, Aws, N);
    k2a_frag<<<(nA + 255)/256, 256, 0, stream>>>(beta, RsOut, Af, N);
    k2c_frag<<<(nB + 255)/256, 256, 0, stream>>>(shaped, posed, Bf);
    k3a_mfma<<<dim3(N/64, 37), 256, 0, stream>>>(Af, Bf, vtemp, verts, N);
    k4a_blend<<<dim3(N, 2), 256, 0, stream>>>(Aws, wts, verts, N);
    k4b_joints<<<(N*64 + 255)/256, 256, 0, stream>>>(verts, Jreg, jpart, N);
    k5_joint_sum<<<(N*48 + 255)/256, 256, 0, stream>>>(jpart, joints, N);
}

// Round 19
// 107.374 us; speedup vs baseline: 1.3562x; 1.0614x over previous
//
#include <hip/hip_runtime.h>
#include <math.h>

#define NJ 16
#define NV 778
#define M3 2334   // NV*3
#define NTB 148   // padded B n-tiles

typedef float f32x4  __attribute__((ext_vector_type(4)));
typedef short bf16x8 __attribute__((ext_vector_type(8)));

__device__ __forceinline__ unsigned short f2bf(float x) {
    unsigned int u = __float_as_uint(x);
    unsigned int r = (u + 0x7FFF + ((u >> 16) & 1)) >> 16;   // RNE
    return (unsigned short)r;
}

// d_out layout (floats): verts [N*2334] | joints [N*48] | Rs [N*144]
// d_ws layout (floats):  A [N*192] | {Afrag|Bfrag}/jpart (time-shared)
// Pipeline: k0 -> k1 -> k2(A->ws) -> k2f(bf16 frags) -> k3a_mfma(verts) ->
//           k4a(blend, A via SCALAR pipe) -> k4b(joint partials) -> k5
//
// LAUNCH-BOUNDS LESSON (R4,R8): second arg w caps VGPR at 256/w -> only (B,1).
// LATENCY LESSONS (R9-R18): (a) multi-barrier per-sample blocks serialize;
// (b) dependent L2 chains -> LDS staging OR (better, R16/R19) scalar pipe for
// wave-uniform data: s_load + SGPR-operand v_fma, no LDS, no barrier;
// (c) matmul-shaped work with K>=16 belongs on MFMA (R18: 52 -> ~12 us).

// ---------------- K0: SJ[b,j,c] = sum_v shapedirs[b,v,c]*Jreg[v,j]; b==10 -> vtemp
__global__ __launch_bounds__(64) void k0_prep(
    const float* __restrict__ shapedirs,
    const float* __restrict__ Jreg,
    const float* __restrict__ vtemp,
    float* __restrict__ SJJT)   // 528 floats
{
    int b = blockIdx.x / 16;    // 0..9 = shapedirs row, 10 = vtemp
    int j = blockIdx.x % 16;
    int t = threadIdx.x;
    const float* src = (b < 10) ? (shapedirs + (size_t)b * M3) : vtemp;
    float a0 = 0.f, a1 = 0.f, a2 = 0.f;
    for (int v = t; v < NV; v += 64) {
        float jr = Jreg[v * 16 + j];
        a0 = fmaf(src[v*3 + 0], jr, a0);
        a1 = fmaf(src[v*3 + 1], jr, a1);
        a2 = fmaf(src[v*3 + 2], jr, a2);
    }
#pragma unroll
    for (int m = 1; m < 64; m <<= 1) {
        a0 += __shfl_xor(a0, m);
        a1 += __shfl_xor(a1, m);
        a2 += __shfl_xor(a2, m);
    }
    if (t == 0) {
        int base = (b < 10) ? (b*48 + j*3) : (480 + j*3);
        SJJT[base + 0] = a0;
        SJJT[base + 1] = a1;
        SJJT[base + 2] = a2;
    }
}

// ---------------- K1: Rodrigues, one thread per (n, joint)
__global__ __launch_bounds__(256) void k1_rodrigues(
    const float* __restrict__ theta, float* __restrict__ RsOut, int N)
{
    int idx = blockIdx.x * 256 + threadIdx.x;
    if (idx >= N * NJ) return;
    int n = idx >> 4;
    int j = idx & 15;
    float t0 = theta[n*48 + j*3 + 0];
    float t1 = theta[n*48 + j*3 + 1];
    float t2 = theta[n*48 + j*3 + 2];
    const float eps = 1e-8f;
    float a0 = t0 + eps, a1 = t1 + eps, a2 = t2 + eps;
    float angle = sqrtf(a0*a0 + a1*a1 + a2*a2);
    float inv  = 1.0f / angle;
    float half = 0.5f * angle;
    float sh = sinf(half), chh = cosf(half);
    float qw = chh;
    float qx = sh * t0 * inv;
    float qy = sh * t1 * inv;
    float qz = sh * t2 * inv;
    float qn = 1.0f / sqrtf(qw*qw + qx*qx + qy*qy + qz*qz);
    qw *= qn; qx *= qn; qy *= qn; qz *= qn;
    float w2=qw*qw, x2=qx*qx, y2=qy*qy, z2=qz*qz;
    float wx=qw*qx, wy=qw*qy, wz=qw*qz;
    float xy=qx*qy, xz=qx*qz, yz=qy*qz;
    float* R = RsOut + (size_t)idx * 9;
    R[0] = w2 + x2 - y2 - z2;
    R[1] = 2.f*(xy - wz);
    R[2] = 2.f*(wy + xz);
    R[3] = 2.f*(wz + xy);
    R[4] = w2 - x2 + y2 - z2;
    R[5] = 2.f*(yz - wx);
    R[6] = 2.f*(xz - wy);
    R[7] = 2.f*(wx + yz);
    R[8] = w2 - x2 - y2 + z2;
}

// ---------------- K2: kinematic chain -> A into d_ws (192 floats / sample)
__global__ __launch_bounds__(64) void k2_chain(
    const float* __restrict__ beta,
    const float* __restrict__ Rs,     // d_out Rs region
    const float* __restrict__ SJJT,   // 528 floats
    float* __restrict__ Aws,          // d_ws; A[n] at n*192
    int N)
{
    __shared__ float sS[528];
    for (int i = threadIdx.x; i < 528; i += 64) sS[i] = SJJT[i];
    __syncthreads();
    int gid = blockIdx.x * 64 + threadIdx.x;
    if (gid >= N * 5) return;
    int n  = gid / 5;
    int ch = gid % 5;

    float b[10];
#pragma unroll
    for (int i = 0; i < 10; ++i) b[i] = beta[n*10 + i];

    int jidx[4];
    jidx[0] = 0; jidx[1] = ch*3 + 1; jidx[2] = ch*3 + 2; jidx[3] = ch*3 + 3;
    float J[4][3];
#pragma unroll
    for (int q = 0; q < 4; ++q) {
        int j = jidx[q];
#pragma unroll
        for (int c = 0; c < 3; ++c) {
            float acc = sS[480 + j*3 + c];
#pragma unroll
            for (int qq = 0; qq < 10; ++qq)
                acc = fmaf(b[qq], sS[qq*48 + j*3 + c], acc);
            J[q][c] = acc;
        }
    }

    const float* Rn = Rs + (size_t)n * 144;
    float* An = Aws + (size_t)n * 192;

    float GpR[9], Gpt[3];
#pragma unroll
    for (int r = 0; r < 3; ++r) {
        GpR[r*3+0] =  Rn[r*3+0];
        GpR[r*3+1] = -Rn[r*3+1];
        GpR[r*3+2] = -Rn[r*3+2];
    }
    Gpt[0] = J[0][0]; Gpt[1] = J[0][1]; Gpt[2] = J[0][2];

    if (ch == 0) {
#pragma unroll
        for (int r = 0; r < 3; ++r) {
            float rel = GpR[r*3+0]*J[0][0] + GpR[r*3+1]*J[0][1] + GpR[r*3+2]*J[0][2];
            An[r*4 + 0] = GpR[r*3+0];
            An[r*4 + 1] = GpR[r*3+1];
            An[r*4 + 2] = GpR[r*3+2];
            An[r*4 + 3] = Gpt[r] - rel;
        }
    }

#pragma unroll
    for (int st = 0; st < 3; ++st) {
        int i = jidx[st+1];
        const float* Ri = Rn + (size_t)i * 9;
        float t0 = J[st+1][0] - J[st][0];
        float t1 = J[st+1][1] - J[st][1];
        float t2 = J[st+1][2] - J[st][2];
        float GR[9], Gt[3];
#pragma unroll
        for (int r = 0; r < 3; ++r) {
#pragma unroll
            for (int c = 0; c < 3; ++c)
                GR[r*3+c] = GpR[r*3+0]*Ri[c] + GpR[r*3+1]*Ri[3+c] + GpR[r*3+2]*Ri[6+c];
            Gt[r] = GpR[r*3+0]*t0 + GpR[r*3+1]*t1 + GpR[r*3+2]*t2 + Gpt[r];
        }
#pragma unroll
        for (int r = 0; r < 3; ++r) {
            float rel = GR[r*3+0]*J[st+1][0] + GR[r*3+1]*J[st+1][1] + GR[r*3+2]*J[st+1][2];
            An[i*12 + r*4 + 0] = GR[r*3+0];
            An[i*12 + r*4 + 1] = GR[r*3+1];
            An[i*12 + r*4 + 2] = GR[r*3+2];
            An[i*12 + r*4 + 3] = Gt[r] - rel;
        }
#pragma unroll
        for (int r = 0; r < 9; ++r) GpR[r] = GR[r];
        Gpt[0] = Gt[0]; Gpt[1] = Gt[1]; Gpt[2] = Gt[2];
    }
}

// ---------------- K2f: both MFMA fragment packs in one launch.
// First nA threads: A-frags; next nB threads: B-frags.
__global__ __launch_bounds__(256) void k2f_frag(
    const float* __restrict__ beta,
    const float* __restrict__ Rs,
    const float* __restrict__ shapedirs,
    const float* __restrict__ posedirs,
    bf16x8* __restrict__ Af,
    bf16x8* __restrict__ Bf,
    int N)
{
    int idx = blockIdx.x * 256 + threadIdx.x;
    int nA = (N / 16) * 5 * 64;
    int nB = NTB * 5 * 64;
    if (idx < nA) {
        int lane = idx & 63;
        int ks   = (idx >> 6) % 5;
        int mt   = idx / 320;
        int n  = mt * 16 + (lane & 15);
        int k0 = ks * 32 + (lane >> 4) * 8;
        bf16x8 o;
#pragma unroll
        for (int j = 0; j < 8; ++j) {
            int k = k0 + j;
            float val;
            if (k < 10) {
                val = beta[(size_t)n * 10 + k];
            } else if (k < 145) {
                int kk = k - 10;
                int rr = kk % 9;
                val = Rs[(size_t)n * 144 + 9 + kk];
                if ((rr & 3) == 0) val -= 1.f;
            } else {
                val = 0.f;
            }
            o[j] = (short)f2bf(val);
        }
        Af[idx] = o;
    } else if (idx < nA + nB) {
        int bidx = idx - nA;
        int lane = bidx & 63;
        int ks   = (bidx >> 6) % 5;
        int nt   = bidx / 320;
        int col = nt * 16 + (lane & 15);
        int k0  = ks * 32 + (lane >> 4) * 8;
        bf16x8 o;
#pragma unroll
        for (int j = 0; j < 8; ++j) {
            int k = k0 + j;
            float val = 0.f;
            if (col < M3) {
                if (k < 10)       val = shapedirs[(size_t)k * M3 + col];
                else if (k < 145) val = posedirs[(size_t)(k - 10) * M3 + col];
            }
            o[j] = (short)f2bf(val);
        }
        Bf[bidx] = o;
    }
}

// ---------------- K3a: MFMA GEMM. One wave computes C tile 16 rows x 64 cols.
__global__ __launch_bounds__(256, 1) void k3a_mfma(
    const bf16x8* __restrict__ Af,      // [(N/16)][5][64]
    const bf16x8* __restrict__ Bf,      // [NTB][5][64]
    const float* __restrict__ vtemp,
    float* __restrict__ verts,
    int N)
{
    const int tid  = threadIdx.x;
    const int w    = tid >> 6;
    const int lane = tid & 63;
    const int mt   = blockIdx.x * 4 + w;
    const int nt0  = blockIdx.y * 4;

    f32x4 acc0 = {0.f,0.f,0.f,0.f};
    f32x4 acc1 = {0.f,0.f,0.f,0.f};
    f32x4 acc2 = {0.f,0.f,0.f,0.f};
    f32x4 acc3 = {0.f,0.f,0.f,0.f};

    const bf16x8* Ab = Af + (size_t)mt * 5 * 64 + lane;
    const bf16x8* Bb = Bf + lane;

#pragma unroll
    for (int ks = 0; ks < 5; ++ks) {
        bf16x8 a  = Ab[ks * 64];
        bf16x8 b0 = Bb[((size_t)(nt0+0) * 5 + ks) * 64];
        bf16x8 b1 = Bb[((size_t)(nt0+1) * 5 + ks) * 64];
        bf16x8 b2 = Bb[((size_t)(nt0+2) * 5 + ks) * 64];
        bf16x8 b3 = Bb[((size_t)(nt0+3) * 5 + ks) * 64];
        acc0 = __builtin_amdgcn_mfma_f32_16x16x32_bf16(a, b0, acc0, 0, 0, 0);
        acc1 = __builtin_amdgcn_mfma_f32_16x16x32_bf16(a, b1, acc1, 0, 0, 0);
        acc2 = __builtin_amdgcn_mfma_f32_16x16x32_bf16(a, b2, acc2, 0, 0, 0);
        acc3 = __builtin_amdgcn_mfma_f32_16x16x32_bf16(a, b3, acc3, 0, 0, 0);
    }

    // C/D layout: col = lane&15, row = (lane>>4)*4 + r  [m89-verified]
    const int row0 = mt * 16 + (lane >> 4) * 4;
    const int cb   = (lane & 15);

#define EPI(accq, q_) { \
    int col = (nt0 + q_) * 16 + cb; \
    if (col < M3) { \
        float vt = vtemp[col]; \
        float* o = verts + (size_t)row0 * M3 + col; \
        o[0]        = accq[0] + vt; \
        o[M3]       = accq[1] + vt; \
        o[2*M3]     = accq[2] + vt; \
        o[3*(size_t)M3] = accq[3] + vt; \
    } }
    EPI(acc0, 0) EPI(acc1, 1) EPI(acc2, 2) EPI(acc3, 3)
#undef EPI
}

// ---------------- K4a: LBS blend, A via SCALAR pipe (wave-uniform s_load).
// No LDS, no barrier. grid (N, 2); 2 verts/thread. Each v_fma uses one SGPR
// (A element) + VGPRs -> legal and issue-efficient.
__global__ __launch_bounds__(256, 1) void k4a_blend(
    const float* __restrict__ Aws,      // d_ws
    const float* __restrict__ weights,
    float* verts,                       // in-place
    int N)
{
    typedef float f32x16v __attribute__((ext_vector_type(16)));
    const int n   = blockIdx.x;
    const int q   = blockIdx.y;
    const int tid = threadIdx.x;

    const float* An = Aws + (size_t)n * 192;    // uniform -> s_load path

    const int v0 = q * 512 + tid;               // always < 778
    const int v1 = v0 + 256;                    // q=1: 768..1023 -> guard
    const bool m1 = v1 < NV;
    const int c1 = m1 ? v1 : (NV - 1);

    float* vp0 = verts + (size_t)n * M3 + (size_t)v0 * 3;
    float* vp1 = verts + (size_t)n * M3 + (size_t)c1 * 3;
    float x0 = vp0[0], y0 = vp0[1], z0 = vp0[2];
    float x1 = vp1[0], y1 = vp1[1], z1 = vp1[2];
    f32x16v w0 = *reinterpret_cast<const f32x16v*>(&weights[(size_t)v0 * 16]);
    f32x16v w1 = *reinterpret_cast<const f32x16v*>(&weights[(size_t)c1 * 16]);

    float o0x=0.f,o0y=0.f,o0z=0.f, o1x=0.f,o1y=0.f,o1z=0.f;

#define BJA2(j_) { \
    float a0=An[(j_)*12+0],  a1=An[(j_)*12+1],  a2 =An[(j_)*12+2],  a3 =An[(j_)*12+3]; \
    float a4=An[(j_)*12+4],  a5=An[(j_)*12+5],  a6 =An[(j_)*12+6],  a7 =An[(j_)*12+7]; \
    float a8=An[(j_)*12+8],  a9=An[(j_)*12+9],  a10=An[(j_)*12+10], a11=An[(j_)*12+11]; \
    float X,Y,Z; \
    X = fmaf(a0,x0, fmaf(a1,y0, fmaf(a2,z0, a3))); \
    Y = fmaf(a4,x0, fmaf(a5,y0, fmaf(a6,z0, a7))); \
    Z = fmaf(a8,x0, fmaf(a9,y0, fmaf(a10,z0, a11))); \
    o0x = fmaf(w0[j_], X, o0x); o0y = fmaf(w0[j_], Y, o0y); o0z = fmaf(w0[j_], Z, o0z); \
    X = fmaf(a0,x1, fmaf(a1,y1, fmaf(a2,z1, a3))); \
    Y = fmaf(a4,x1, fmaf(a5,y1, fmaf(a6,z1, a7))); \
    Z = fmaf(a8,x1, fmaf(a9,y1, fmaf(a10,z1, a11))); \
    o1x = fmaf(w1[j_], X, o1x); o1y = fmaf(w1[j_], Y, o1y); o1z = fmaf(w1[j_], Z, o1z); }

    BJA2(0)  BJA2(1)  BJA2(2)  BJA2(3)  BJA2(4)  BJA2(5)  BJA2(6)  BJA2(7)
    BJA2(8)  BJA2(9)  BJA2(10) BJA2(11) BJA2(12) BJA2(13) BJA2(14) BJA2(15)
#undef BJA2

    vp0[0] = o0x; vp0[1] = o0y; vp0[2] = o0z;
    if (m1) { vp1[0] = o1x; vp1[1] = o1y; vp1[2] = o1z; }
}

// ---------------- K4b: joint partials, barrier-free. One thread per
// (n, chunk, j), j fastest (coalesced Jreg; verts broadcast across j-lanes).
__global__ __launch_bounds__(256, 1) void k4b_joints(
    const float* __restrict__ verts,
    const float* __restrict__ Jreg,
    float* __restrict__ jpart,          // d_ws + N*192 (overwrites frags)
    int N)
{
    int gid = blockIdx.x * 256 + threadIdx.x;   // total N*4*16
    if (gid >= N * 64) return;
    int j  = gid & 15;
    int c4 = (gid >> 4) & 3;
    int n  = gid >> 6;

    int vbeg = c4 * 195;
    int vend = vbeg + 195; if (vend > NV) vend = NV;

    const float* vp = verts + (size_t)n * M3;
    float a0 = 0.f, a1 = 0.f, a2 = 0.f;
#pragma unroll 4
    for (int v = vbeg; v < vend; ++v) {
        float jr = Jreg[(size_t)v * 16 + j];
        float x = vp[v*3 + 0], y = vp[v*3 + 1], z = vp[v*3 + 2];
        a0 = fmaf(jr, x, a0);
        a1 = fmaf(jr, y, a1);
        a2 = fmaf(jr, z, a2);
    }
    float* o = jpart + (size_t)n * 192 + c4 * 48 + j * 3;
    o[0] = a0; o[1] = a1; o[2] = a2;
}

// ---------------- K5: joints[n*48+r] = sum_c4 jpart[n*192 + c4*48 + r]
__global__ __launch_bounds__(256) void k5_joint_sum(
    const float* __restrict__ jpart, float* __restrict__ joints, int N)
{
    int i = blockIdx.x * 256 + threadIdx.x;     // N*48
    if (i >= N * 48) return;
    int n = i / 48;
    int r = i - n * 48;
    const float* p = jpart + (size_t)n * 192 + r;
    joints[i] = p[0] + p[48] + p[96] + p[144];
}

extern "C" void kernel_launch(void* const* d_in, const int* in_sizes, int n_in,
                              void* d_out, int out_size, void* d_ws, size_t ws_size,
                              hipStream_t stream)
{
    const float* beta   = (const float*)d_in[0];
    const float* theta  = (const float*)d_in[1];
    const float* vtemp  = (const float*)d_in[2];
    const float* shaped = (const float*)d_in[3];
    const float* Jreg   = (const float*)d_in[4];
    const float* posed  = (const float*)d_in[5];
    const float* wts    = (const float*)d_in[6];
    float* out = (float*)d_out;
    const int N = in_sizes[0] / 10;   // 4096

    float* verts  = out;                            // N*2334
    float* joints = out + (size_t)N * M3;           // N*48
    float* RsOut  = joints + (size_t)N * 48;        // N*144
    float* Aws    = (float*)d_ws;                   // N*192 floats = 3.1 MB
    float*  fbase = Aws + (size_t)N * 192;
    bf16x8* Af    = (bf16x8*)fbase;                          // (N/16)*5*64 *16B
    bf16x8* Bf    = (bf16x8*)(fbase + (size_t)(N/16)*5*64*4);// NTB*5*64 *16B
    float*  jpart = fbase;                                   // k4b overwrites

    const int nA = (N / 16) * 5 * 64;
    const int nB = NTB * 5 * 64;

    k0_prep<<<176, 64, 0, stream>>>(shaped, Jreg, vtemp, joints);
    k1_rodrigues<<<(N*NJ + 255)/256, 256, 0, stream>>>(theta, RsOut, N);
    k2_chain<<<(N*5 + 63)/64, 64, 0, stream>>>(beta, RsOut, joints, Aws, N);
    k2f_frag<<<(nA + nB + 255)/256, 256, 0, stream>>>(beta, RsOut, shaped, posed, Af, Bf, N);
    k3a_mfma<<<dim3(N/64, 37), 256, 0, stream>>>(Af, Bf, vtemp, verts, N);
    k4a_blend<<<dim3(N, 2), 256, 0, stream>>>(Aws, wts, verts, N);
    k4b_joints<<<(N*64 + 255)/256, 256, 0, stream>>>(verts, Jreg, jpart, N);
    k5_joint_sum<<<(N*48 + 255)/256, 256, 0, stream>>>(jpart, joints, N);
}

// Round 20
// 99.322 us; speedup vs baseline: 1.4662x; 1.0811x over previous
//
#include <hip/hip_runtime.h>
#include <math.h>

#define NJ 16
#define NV 778
#define M3 2334   // NV*3
#define NTB 148   // padded B n-tiles

typedef float f32x4  __attribute__((ext_vector_type(4)));
typedef short bf16x8 __attribute__((ext_vector_type(8)));

__device__ __forceinline__ unsigned short f2bf(float x) {
    unsigned int u = __float_as_uint(x);
    unsigned int r = (u + 0x7FFF + ((u >> 16) & 1)) >> 16;   // RNE
    return (unsigned short)r;
}

// d_out layout (floats): verts [N*2334] | joints [N*48] | Rs [N*144]
// d_ws layout (floats):  A [N*192] | {Afrag|Bfrag}
// Pipeline (5 launches): k01(SJJT+Rs) -> k2m(A + bf16 frags) -> k3a_mfma ->
//                        k4a(blend, scalar-pipe A) -> k4b(joints, fused sum)
//
// LAUNCH-BOUNDS LESSON (R4,R8): second arg w caps VGPR at 256/w -> only (B,1).
// LATENCY LESSONS (R9-R19): (a) multi-barrier per-sample blocks serialize;
// (b) wave-uniform data -> scalar pipe (s_load + SGPR v_fma), not LDS;
// (c) matmul-shaped K>=16 work belongs on MFMA; (d) serial launch chains cost
// ~3-4us per dependent launch -- merge independent prep kernels.

// ---------------- K01: fused k0 (SJ/JT wave-reductions) + k1 (Rodrigues).
// Blocks [0,44): 4 wave-tasks each for the 176 (b,j) reductions.
// Blocks [44, ...): one thread per (n, joint) Rodrigues.
__global__ __launch_bounds__(256, 1) void k01_prep(
    const float* __restrict__ shapedirs,
    const float* __restrict__ Jreg,
    const float* __restrict__ vtemp,
    const float* __restrict__ theta,
    float* __restrict__ SJJT,     // joints region, 528 floats
    float* __restrict__ RsOut,
    int N)
{
    const int tid = threadIdx.x;
    if (blockIdx.x < 44) {
        int task = blockIdx.x * 4 + (tid >> 6);   // 0..175
        int lane = tid & 63;
        if (task < 176) {
            int b = task >> 4;      // 0..10
            int j = task & 15;
            const float* src = (b < 10) ? (shapedirs + (size_t)b * M3) : vtemp;
            float a0 = 0.f, a1 = 0.f, a2 = 0.f;
            for (int v = lane; v < NV; v += 64) {
                float jr = Jreg[v * 16 + j];
                a0 = fmaf(src[v*3 + 0], jr, a0);
                a1 = fmaf(src[v*3 + 1], jr, a1);
                a2 = fmaf(src[v*3 + 2], jr, a2);
            }
#pragma unroll
            for (int m = 1; m < 64; m <<= 1) {
                a0 += __shfl_xor(a0, m);
                a1 += __shfl_xor(a1, m);
                a2 += __shfl_xor(a2, m);
            }
            if (lane == 0) {
                int base = (b < 10) ? (b*48 + j*3) : (480 + j*3);
                SJJT[base + 0] = a0;
                SJJT[base + 1] = a1;
                SJJT[base + 2] = a2;
            }
        }
        return;
    }
    int idx = (blockIdx.x - 44) * 256 + tid;
    if (idx >= N * NJ) return;
    int n = idx >> 4;
    int j = idx & 15;
    float t0 = theta[n*48 + j*3 + 0];
    float t1 = theta[n*48 + j*3 + 1];
    float t2 = theta[n*48 + j*3 + 2];
    const float eps = 1e-8f;
    float a0 = t0 + eps, a1 = t1 + eps, a2 = t2 + eps;
    float angle = sqrtf(a0*a0 + a1*a1 + a2*a2);
    float inv  = 1.0f / angle;
    float half = 0.5f * angle;
    float sh = sinf(half), chh = cosf(half);
    float qw = chh;
    float qx = sh * t0 * inv;
    float qy = sh * t1 * inv;
    float qz = sh * t2 * inv;
    float qn = 1.0f / sqrtf(qw*qw + qx*qx + qy*qy + qz*qz);
    qw *= qn; qx *= qn; qy *= qn; qz *= qn;
    float w2=qw*qw, x2=qx*qx, y2=qy*qy, z2=qz*qz;
    float wx=qw*qx, wy=qw*qy, wz=qw*qz;
    float xy=qx*qy, xz=qx*qz, yz=qy*qz;
    float* R = RsOut + (size_t)idx * 9;
    R[0] = w2 + x2 - y2 - z2;
    R[1] = 2.f*(xy - wz);
    R[2] = 2.f*(wy + xz);
    R[3] = 2.f*(wz + xy);
    R[4] = w2 - x2 + y2 - z2;
    R[5] = 2.f*(yz - wx);
    R[6] = 2.f*(xz - wy);
    R[7] = 2.f*(wx + yz);
    R[8] = w2 - x2 - y2 + z2;
}

// ---------------- K2M: fused k2 (kinematic chain -> A) + k2f (bf16 frags).
// Blocks [0, KB2): chain, 256 threads = 4x the old 64-thread layout.
// Blocks [KB2, ...): fragment packing.
__global__ __launch_bounds__(256, 1) void k2m(
    const float* __restrict__ beta,
    const float* __restrict__ Rs,
    const float* __restrict__ SJJT,
    const float* __restrict__ shapedirs,
    const float* __restrict__ posedirs,
    float* __restrict__ Aws,
    bf16x8* __restrict__ Af,
    bf16x8* __restrict__ Bf,
    int N)
{
    const int tid = threadIdx.x;
    const int KB2 = (N * 5 + 255) / 256;        // 80 for N=4096
    if (blockIdx.x < KB2) {
        __shared__ float sS[528];
        for (int i = tid; i < 528; i += 256) sS[i] = SJJT[i];
        __syncthreads();
        int gid = blockIdx.x * 256 + tid;
        if (gid >= N * 5) return;
        int n  = gid / 5;
        int ch = gid % 5;

        float b[10];
#pragma unroll
        for (int i = 0; i < 10; ++i) b[i] = beta[n*10 + i];

        int jidx[4];
        jidx[0] = 0; jidx[1] = ch*3 + 1; jidx[2] = ch*3 + 2; jidx[3] = ch*3 + 3;
        float J[4][3];
#pragma unroll
        for (int q = 0; q < 4; ++q) {
            int j = jidx[q];
#pragma unroll
            for (int c = 0; c < 3; ++c) {
                float acc = sS[480 + j*3 + c];
#pragma unroll
                for (int qq = 0; qq < 10; ++qq)
                    acc = fmaf(b[qq], sS[qq*48 + j*3 + c], acc);
                J[q][c] = acc;
            }
        }

        const float* Rn = Rs + (size_t)n * 144;
        float* An = Aws + (size_t)n * 192;

        float GpR[9], Gpt[3];
#pragma unroll
        for (int r = 0; r < 3; ++r) {
            GpR[r*3+0] =  Rn[r*3+0];
            GpR[r*3+1] = -Rn[r*3+1];
            GpR[r*3+2] = -Rn[r*3+2];
        }
        Gpt[0] = J[0][0]; Gpt[1] = J[0][1]; Gpt[2] = J[0][2];

        if (ch == 0) {
#pragma unroll
            for (int r = 0; r < 3; ++r) {
                float rel = GpR[r*3+0]*J[0][0] + GpR[r*3+1]*J[0][1] + GpR[r*3+2]*J[0][2];
                An[r*4 + 0] = GpR[r*3+0];
                An[r*4 + 1] = GpR[r*3+1];
                An[r*4 + 2] = GpR[r*3+2];
                An[r*4 + 3] = Gpt[r] - rel;
            }
        }

#pragma unroll
        for (int st = 0; st < 3; ++st) {
            int i = jidx[st+1];
            const float* Ri = Rn + (size_t)i * 9;
            float t0 = J[st+1][0] - J[st][0];
            float t1 = J[st+1][1] - J[st][1];
            float t2 = J[st+1][2] - J[st][2];
            float GR[9], Gt[3];
#pragma unroll
            for (int r = 0; r < 3; ++r) {
#pragma unroll
                for (int c = 0; c < 3; ++c)
                    GR[r*3+c] = GpR[r*3+0]*Ri[c] + GpR[r*3+1]*Ri[3+c] + GpR[r*3+2]*Ri[6+c];
                Gt[r] = GpR[r*3+0]*t0 + GpR[r*3+1]*t1 + GpR[r*3+2]*t2 + Gpt[r];
            }
#pragma unroll
            for (int r = 0; r < 3; ++r) {
                float rel = GR[r*3+0]*J[st+1][0] + GR[r*3+1]*J[st+1][1] + GR[r*3+2]*J[st+1][2];
                An[i*12 + r*4 + 0] = GR[r*3+0];
                An[i*12 + r*4 + 1] = GR[r*3+1];
                An[i*12 + r*4 + 2] = GR[r*3+2];
                An[i*12 + r*4 + 3] = Gt[r] - rel;
            }
#pragma unroll
            for (int r = 0; r < 9; ++r) GpR[r] = GR[r];
            Gpt[0] = Gt[0]; Gpt[1] = Gt[1]; Gpt[2] = Gt[2];
        }
        return;
    }

    // fragment packing
    int idx = (blockIdx.x - KB2) * 256 + tid;
    int nA = (N / 16) * 5 * 64;
    int nB = NTB * 5 * 64;
    if (idx < nA) {
        int lane = idx & 63;
        int ks   = (idx >> 6) % 5;
        int mt   = idx / 320;
        int n  = mt * 16 + (lane & 15);
        int k0 = ks * 32 + (lane >> 4) * 8;
        bf16x8 o;
#pragma unroll
        for (int j = 0; j < 8; ++j) {
            int k = k0 + j;
            float val;
            if (k < 10) {
                val = beta[(size_t)n * 10 + k];
            } else if (k < 145) {
                int kk = k - 10;
                int rr = kk % 9;
                val = Rs[(size_t)n * 144 + 9 + kk];
                if ((rr & 3) == 0) val -= 1.f;
            } else {
                val = 0.f;
            }
            o[j] = (short)f2bf(val);
        }
        Af[idx] = o;
    } else if (idx < nA + nB) {
        int bidx = idx - nA;
        int lane = bidx & 63;
        int ks   = (bidx >> 6) % 5;
        int nt   = bidx / 320;
        int col = nt * 16 + (lane & 15);
        int k0  = ks * 32 + (lane >> 4) * 8;
        bf16x8 o;
#pragma unroll
        for (int j = 0; j < 8; ++j) {
            int k = k0 + j;
            float val = 0.f;
            if (col < M3) {
                if (k < 10)       val = shapedirs[(size_t)k * M3 + col];
                else if (k < 145) val = posedirs[(size_t)(k - 10) * M3 + col];
            }
            o[j] = (short)f2bf(val);
        }
        Bf[bidx] = o;
    }
}

// ---------------- K3a: MFMA GEMM. One wave computes C tile 16 rows x 64 cols.
__global__ __launch_bounds__(256, 1) void k3a_mfma(
    const bf16x8* __restrict__ Af,      // [(N/16)][5][64]
    const bf16x8* __restrict__ Bf,      // [NTB][5][64]
    const float* __restrict__ vtemp,
    float* __restrict__ verts,
    int N)
{
    const int tid  = threadIdx.x;
    const int w    = tid >> 6;
    const int lane = tid & 63;
    const int mt   = blockIdx.x * 4 + w;
    const int nt0  = blockIdx.y * 4;

    f32x4 acc0 = {0.f,0.f,0.f,0.f};
    f32x4 acc1 = {0.f,0.f,0.f,0.f};
    f32x4 acc2 = {0.f,0.f,0.f,0.f};
    f32x4 acc3 = {0.f,0.f,0.f,0.f};

    const bf16x8* Ab = Af + (size_t)mt * 5 * 64 + lane;
    const bf16x8* Bb = Bf + lane;

#pragma unroll
    for (int ks = 0; ks < 5; ++ks) {
        bf16x8 a  = Ab[ks * 64];
        bf16x8 b0 = Bb[((size_t)(nt0+0) * 5 + ks) * 64];
        bf16x8 b1 = Bb[((size_t)(nt0+1) * 5 + ks) * 64];
        bf16x8 b2 = Bb[((size_t)(nt0+2) * 5 + ks) * 64];
        bf16x8 b3 = Bb[((size_t)(nt0+3) * 5 + ks) * 64];
        acc0 = __builtin_amdgcn_mfma_f32_16x16x32_bf16(a, b0, acc0, 0, 0, 0);
        acc1 = __builtin_amdgcn_mfma_f32_16x16x32_bf16(a, b1, acc1, 0, 0, 0);
        acc2 = __builtin_amdgcn_mfma_f32_16x16x32_bf16(a, b2, acc2, 0, 0, 0);
        acc3 = __builtin_amdgcn_mfma_f32_16x16x32_bf16(a, b3, acc3, 0, 0, 0);
    }

    // C/D layout: col = lane&15, row = (lane>>4)*4 + r  [m89-verified]
    const int row0 = mt * 16 + (lane >> 4) * 4;
    const int cb   = (lane & 15);

#define EPI(accq, q_) { \
    int col = (nt0 + q_) * 16 + cb; \
    if (col < M3) { \
        float vt = vtemp[col]; \
        float* o = verts + (size_t)row0 * M3 + col; \
        o[0]        = accq[0] + vt; \
        o[M3]       = accq[1] + vt; \
        o[2*M3]     = accq[2] + vt; \
        o[3*(size_t)M3] = accq[3] + vt; \
    } }
    EPI(acc0, 0) EPI(acc1, 1) EPI(acc2, 2) EPI(acc3, 3)
#undef EPI
}

// ---------------- K4a: LBS blend, A via SCALAR pipe. grid (N, 2); 2 verts/thr.
__global__ __launch_bounds__(256, 1) void k4a_blend(
    const float* __restrict__ Aws,      // d_ws
    const float* __restrict__ weights,
    float* verts,                       // in-place
    int N)
{
    typedef float f32x16v __attribute__((ext_vector_type(16)));
    const int n   = blockIdx.x;
    const int q   = blockIdx.y;
    const int tid = threadIdx.x;

    const float* An = Aws + (size_t)n * 192;    // uniform -> s_load path

    const int v0 = q * 512 + tid;               // always < 778
    const int v1 = v0 + 256;                    // q=1: 768..1023 -> guard
    const bool m1 = v1 < NV;
    const int c1 = m1 ? v1 : (NV - 1);

    float* vp0 = verts + (size_t)n * M3 + (size_t)v0 * 3;
    float* vp1 = verts + (size_t)n * M3 + (size_t)c1 * 3;
    float x0 = vp0[0], y0 = vp0[1], z0 = vp0[2];
    float x1 = vp1[0], y1 = vp1[1], z1 = vp1[2];
    f32x16v w0 = *reinterpret_cast<const f32x16v*>(&weights[(size_t)v0 * 16]);
    f32x16v w1 = *reinterpret_cast<const f32x16v*>(&weights[(size_t)c1 * 16]);

    float o0x=0.f,o0y=0.f,o0z=0.f, o1x=0.f,o1y=0.f,o1z=0.f;

#define BJA2(j_) { \
    float a0=An[(j_)*12+0],  a1=An[(j_)*12+1],  a2 =An[(j_)*12+2],  a3 =An[(j_)*12+3]; \
    float a4=An[(j_)*12+4],  a5=An[(j_)*12+5],  a6 =An[(j_)*12+6],  a7 =An[(j_)*12+7]; \
    float a8=An[(j_)*12+8],  a9=An[(j_)*12+9],  a10=An[(j_)*12+10], a11=An[(j_)*12+11]; \
    float X,Y,Z; \
    X = fmaf(a0,x0, fmaf(a1,y0, fmaf(a2,z0, a3))); \
    Y = fmaf(a4,x0, fmaf(a5,y0, fmaf(a6,z0, a7))); \
    Z = fmaf(a8,x0, fmaf(a9,y0, fmaf(a10,z0, a11))); \
    o0x = fmaf(w0[j_], X, o0x); o0y = fmaf(w0[j_], Y, o0y); o0z = fmaf(w0[j_], Z, o0z); \
    X = fmaf(a0,x1, fmaf(a1,y1, fmaf(a2,z1, a3))); \
    Y = fmaf(a4,x1, fmaf(a5,y1, fmaf(a6,z1, a7))); \
    Z = fmaf(a8,x1, fmaf(a9,y1, fmaf(a10,z1, a11))); \
    o1x = fmaf(w1[j_], X, o1x); o1y = fmaf(w1[j_], Y, o1y); o1z = fmaf(w1[j_], Z, o1z); }

    BJA2(0)  BJA2(1)  BJA2(2)  BJA2(3)  BJA2(4)  BJA2(5)  BJA2(6)  BJA2(7)
    BJA2(8)  BJA2(9)  BJA2(10) BJA2(11) BJA2(12) BJA2(13) BJA2(14) BJA2(15)
#undef BJA2

    vp0[0] = o0x; vp0[1] = o0y; vp0[2] = o0z;
    if (m1) { vp1[0] = o1x; vp1[1] = o1y; vp1[2] = o1z; }
}

// ---------------- K4b: joint regression, fused final sum. Block = 4 samples,
// 256 threads = 4 x (4 chunks x 16 j). Partials in LDS, one barrier, direct
// joints write (no global round trip, no k5).
__global__ __launch_bounds__(256, 1) void k4b_joints(
    const float* __restrict__ verts,
    const float* __restrict__ Jreg,
    float* __restrict__ joints,
    int N)
{
    __shared__ float part[4][4][48];
    const int tid = threadIdx.x;
    const int nl  = tid >> 6;            // 0..3 local sample
    const int sub = tid & 63;
    const int j   = sub & 15;
    const int c4  = sub >> 4;            // 0..3
    const int n   = blockIdx.x * 4 + nl;

    int vbeg = c4 * 195;
    int vend = vbeg + 195; if (vend > NV) vend = NV;

    const float* vp = verts + (size_t)n * M3;
    float a0 = 0.f, a1 = 0.f, a2 = 0.f;
#pragma unroll 4
    for (int v = vbeg; v < vend; ++v) {
        float jr = Jreg[(size_t)v * 16 + j];
        float x = vp[v*3 + 0], y = vp[v*3 + 1], z = vp[v*3 + 2];
        a0 = fmaf(jr, x, a0);
        a1 = fmaf(jr, y, a1);
        a2 = fmaf(jr, z, a2);
    }
    part[nl][c4][j*3+0] = a0;
    part[nl][c4][j*3+1] = a1;
    part[nl][c4][j*3+2] = a2;
    __syncthreads();

    if (tid < 192) {
        int nl2 = tid / 48;
        int r   = tid % 48;
        float s = part[nl2][0][r] + part[nl2][1][r] + part[nl2][2][r] + part[nl2][3][r];
        joints[(size_t)(blockIdx.x * 4 + nl2) * 48 + r] = s;
    }
}

extern "C" void kernel_launch(void* const* d_in, const int* in_sizes, int n_in,
                              void* d_out, int out_size, void* d_ws, size_t ws_size,
                              hipStream_t stream)
{
    const float* beta   = (const float*)d_in[0];
    const float* theta  = (const float*)d_in[1];
    const float* vtemp  = (const float*)d_in[2];
    const float* shaped = (const float*)d_in[3];
    const float* Jreg   = (const float*)d_in[4];
    const float* posed  = (const float*)d_in[5];
    const float* wts    = (const float*)d_in[6];
    float* out = (float*)d_out;
    const int N = in_sizes[0] / 10;   // 4096

    float* verts  = out;                            // N*2334
    float* joints = out + (size_t)N * M3;           // N*48
    float* RsOut  = joints + (size_t)N * 48;        // N*144
    float* Aws    = (float*)d_ws;                   // N*192 floats = 3.1 MB
    float*  fbase = Aws + (size_t)N * 192;
    bf16x8* Af    = (bf16x8*)fbase;                          // (N/16)*5*64 *16B
    bf16x8* Bf    = (bf16x8*)(fbase + (size_t)(N/16)*5*64*4);// NTB*5*64 *16B

    const int nA = (N / 16) * 5 * 64;
    const int nB = NTB * 5 * 64;
    const int KB2 = (N * 5 + 255) / 256;
    const int kb2f = (nA + nB + 255) / 256;

    // k01: 44 blocks of SJ/JT reductions + Rodrigues blocks
    k01_prep<<<44 + (N*NJ + 255)/256, 256, 0, stream>>>(
        shaped, Jreg, vtemp, theta, joints, RsOut, N);
    // k2m: chain blocks + fragment blocks
    k2m<<<KB2 + kb2f, 256, 0, stream>>>(
        beta, RsOut, joints, shaped, posed, Aws, Af, Bf, N);
    k3a_mfma<<<dim3(N/64, 37), 256, 0, stream>>>(Af, Bf, vtemp, verts, N);
    k4a_blend<<<dim3(N, 2), 256, 0, stream>>>(Aws, wts, verts, N);
    k4b_joints<<<N/4, 256, 0, stream>>>(verts, Jreg, joints, N);
}

// Round 21
// 82.196 us; speedup vs baseline: 1.7716x; 1.2084x over previous
//
#include <hip/hip_runtime.h>
#include <math.h>

#define NJ 16
#define NV 778
#define M3 2334   // NV*3
#define NTB 156   // B n-tiles: 13 col-blocks x 12 subtiles (cols padded past 2334)

typedef float f32x4  __attribute__((ext_vector_type(4)));
typedef float f32x16 __attribute__((ext_vector_type(16)));
typedef short bf16x8 __attribute__((ext_vector_type(8)));

__device__ __forceinline__ unsigned short f2bf(float x) {
    unsigned int u = __float_as_uint(x);
    unsigned int r = (u + 0x7FFF + ((u >> 16) & 1)) >> 16;   // RNE
    return (unsigned short)r;
}

// d_out layout (floats): verts [N*2334] | joints [N*48] | Rs [N*144]
// d_ws layout (floats):  A [N*192] | Afrag (1.31MB) | Bfrag (0.78MB)
// Pipeline (4 launches): k01(SJJT + Rodrigues + B-frags) ->
//   k2m(chain A + A-frags) -> k34(MFMA GEMM + LBS blend fused) -> k4b(joints)
//
// LAUNCH-BOUNDS LESSON (R4,R8): second arg w caps VGPR at 256/w -> only (B,1).
// LATENCY LESSONS (R9-R20): (a) multi-barrier per-sample blocks serialize;
// (b) wave-uniform data -> scalar pipe (readfirstlane + s_load + SGPR v_fma);
// (c) matmul-shaped K>=16 work belongs on MFMA; (d) dependent launches cost
// ~3us each -- merge independent work; (e) producer->consumer global round
// trips (verts) are worth fusing via an LDS tile when tile geometry allows
// (192 cols = 64 whole verts).

// ---------------- K01: SJ/JT reductions + Rodrigues + B-frag packing.
__global__ __launch_bounds__(256, 1) void k01_prep(
    const float* __restrict__ shapedirs,
    const float* __restrict__ posedirs,
    const float* __restrict__ Jreg,
    const float* __restrict__ vtemp,
    const float* __restrict__ theta,
    float* __restrict__ SJJT,     // joints region, 528 floats
    float* __restrict__ RsOut,
    bf16x8* __restrict__ Bf,
    int N)
{
    const int tid = threadIdx.x;
    const int rodBlocks = (N * NJ) / 256;        // 256 for N=4096
    if (blockIdx.x < 44) {
        int task = blockIdx.x * 4 + (tid >> 6);   // 0..175
        int lane = tid & 63;
        if (task < 176) {
            int b = task >> 4;      // 0..10
            int j = task & 15;
            const float* src = (b < 10) ? (shapedirs + (size_t)b * M3) : vtemp;
            float a0 = 0.f, a1 = 0.f, a2 = 0.f;
            for (int v = lane; v < NV; v += 64) {
                float jr = Jreg[v * 16 + j];
                a0 = fmaf(src[v*3 + 0], jr, a0);
                a1 = fmaf(src[v*3 + 1], jr, a1);
                a2 = fmaf(src[v*3 + 2], jr, a2);
            }
#pragma unroll
            for (int m = 1; m < 64; m <<= 1) {
                a0 += __shfl_xor(a0, m);
                a1 += __shfl_xor(a1, m);
                a2 += __shfl_xor(a2, m);
            }
            if (lane == 0) {
                int base = (b < 10) ? (b*48 + j*3) : (480 + j*3);
                SJJT[base + 0] = a0;
                SJJT[base + 1] = a1;
                SJJT[base + 2] = a2;
            }
        }
        return;
    }
    if (blockIdx.x < 44 + rodBlocks) {
        int idx = (blockIdx.x - 44) * 256 + tid;
        int n = idx >> 4;
        int j = idx & 15;
        float t0 = theta[n*48 + j*3 + 0];
        float t1 = theta[n*48 + j*3 + 1];
        float t2 = theta[n*48 + j*3 + 2];
        const float eps = 1e-8f;
        float a0 = t0 + eps, a1 = t1 + eps, a2 = t2 + eps;
        float angle = sqrtf(a0*a0 + a1*a1 + a2*a2);
        float inv  = 1.0f / angle;
        float half = 0.5f * angle;
        float sh = sinf(half), chh = cosf(half);
        float qw = chh;
        float qx = sh * t0 * inv;
        float qy = sh * t1 * inv;
        float qz = sh * t2 * inv;
        float qn = 1.0f / sqrtf(qw*qw + qx*qx + qy*qy + qz*qz);
        qw *= qn; qx *= qn; qy *= qn; qz *= qn;
        float w2=qw*qw, x2=qx*qx, y2=qy*qy, z2=qz*qz;
        float wx=qw*qx, wy=qw*qy, wz=qw*qz;
        float xy=qx*qy, xz=qx*qz, yz=qy*qz;
        float* R = RsOut + (size_t)idx * 9;
        R[0] = w2 + x2 - y2 - z2;
        R[1] = 2.f*(xy - wz);
        R[2] = 2.f*(wy + xz);
        R[3] = 2.f*(wz + xy);
        R[4] = w2 - x2 + y2 - z2;
        R[5] = 2.f*(yz - wx);
        R[6] = 2.f*(xz - wy);
        R[7] = 2.f*(wx + yz);
        R[8] = w2 - x2 - y2 + z2;
        return;
    }
    // B-frag packing (depends only on inputs)
    int idx = (blockIdx.x - 44 - rodBlocks) * 256 + tid;
    int nB = NTB * 5 * 64;
    if (idx >= nB) return;
    int lane = idx & 63;
    int ks   = (idx >> 6) % 5;
    int nt   = idx / 320;
    int col = nt * 16 + (lane & 15);
    int k0  = ks * 32 + (lane >> 4) * 8;
    bf16x8 o;
#pragma unroll
    for (int j = 0; j < 8; ++j) {
        int k = k0 + j;
        float val = 0.f;
        if (col < M3) {
            if (k < 10)       val = shapedirs[(size_t)k * M3 + col];
            else if (k < 145) val = posedirs[(size_t)(k - 10) * M3 + col];
        }
        o[j] = (short)f2bf(val);
    }
    Bf[idx] = o;
}

// ---------------- K2M: kinematic chain -> A, plus A-frag packing.
__global__ __launch_bounds__(256, 1) void k2m(
    const float* __restrict__ beta,
    const float* __restrict__ Rs,
    const float* __restrict__ SJJT,
    float* __restrict__ Aws,
    bf16x8* __restrict__ Af,
    int N)
{
    const int tid = threadIdx.x;
    const int KB2 = (N * 5 + 255) / 256;        // 80 for N=4096
    if (blockIdx.x < KB2) {
        __shared__ float sS[528];
        for (int i = tid; i < 528; i += 256) sS[i] = SJJT[i];
        __syncthreads();
        int gid = blockIdx.x * 256 + tid;
        if (gid >= N * 5) return;
        int n  = gid / 5;
        int ch = gid % 5;

        float b[10];
#pragma unroll
        for (int i = 0; i < 10; ++i) b[i] = beta[n*10 + i];

        int jidx[4];
        jidx[0] = 0; jidx[1] = ch*3 + 1; jidx[2] = ch*3 + 2; jidx[3] = ch*3 + 3;
        float J[4][3];
#pragma unroll
        for (int q = 0; q < 4; ++q) {
            int j = jidx[q];
#pragma unroll
            for (int c = 0; c < 3; ++c) {
                float acc = sS[480 + j*3 + c];
#pragma unroll
                for (int qq = 0; qq < 10; ++qq)
                    acc = fmaf(b[qq], sS[qq*48 + j*3 + c], acc);
                J[q][c] = acc;
            }
        }

        const float* Rn = Rs + (size_t)n * 144;
        float* An = Aws + (size_t)n * 192;

        float GpR[9], Gpt[3];
#pragma unroll
        for (int r = 0; r < 3; ++r) {
            GpR[r*3+0] =  Rn[r*3+0];
            GpR[r*3+1] = -Rn[r*3+1];
            GpR[r*3+2] = -Rn[r*3+2];
        }
        Gpt[0] = J[0][0]; Gpt[1] = J[0][1]; Gpt[2] = J[0][2];

        if (ch == 0) {
#pragma unroll
            for (int r = 0; r < 3; ++r) {
                float rel = GpR[r*3+0]*J[0][0] + GpR[r*3+1]*J[0][1] + GpR[r*3+2]*J[0][2];
                An[r*4 + 0] = GpR[r*3+0];
                An[r*4 + 1] = GpR[r*3+1];
                An[r*4 + 2] = GpR[r*3+2];
                An[r*4 + 3] = Gpt[r] - rel;
            }
        }

#pragma unroll
        for (int st = 0; st < 3; ++st) {
            int i = jidx[st+1];
            const float* Ri = Rn + (size_t)i * 9;
            float t0 = J[st+1][0] - J[st][0];
            float t1 = J[st+1][1] - J[st][1];
            float t2 = J[st+1][2] - J[st][2];
            float GR[9], Gt[3];
#pragma unroll
            for (int r = 0; r < 3; ++r) {
#pragma unroll
                for (int c = 0; c < 3; ++c)
                    GR[r*3+c] = GpR[r*3+0]*Ri[c] + GpR[r*3+1]*Ri[3+c] + GpR[r*3+2]*Ri[6+c];
                Gt[r] = GpR[r*3+0]*t0 + GpR[r*3+1]*t1 + GpR[r*3+2]*t2 + Gpt[r];
            }
#pragma unroll
            for (int r = 0; r < 3; ++r) {
                float rel = GR[r*3+0]*J[st+1][0] + GR[r*3+1]*J[st+1][1] + GR[r*3+2]*J[st+1][2];
                An[i*12 + r*4 + 0] = GR[r*3+0];
                An[i*12 + r*4 + 1] = GR[r*3+1];
                An[i*12 + r*4 + 2] = GR[r*3+2];
                An[i*12 + r*4 + 3] = Gt[r] - rel;
            }
#pragma unroll
            for (int r = 0; r < 9; ++r) GpR[r] = GR[r];
            Gpt[0] = Gt[0]; Gpt[1] = Gt[1]; Gpt[2] = Gt[2];
        }
        return;
    }

    // A-frag packing
    int idx = (blockIdx.x - KB2) * 256 + tid;
    int nA = (N / 16) * 5 * 64;
    if (idx >= nA) return;
    int lane = idx & 63;
    int ks   = (idx >> 6) % 5;
    int mt   = idx / 320;
    int n  = mt * 16 + (lane & 15);
    int k0 = ks * 32 + (lane >> 4) * 8;
    bf16x8 o;
#pragma unroll
    for (int j = 0; j < 8; ++j) {
        int k = k0 + j;
        float val;
        if (k < 10) {
            val = beta[(size_t)n * 10 + k];
        } else if (k < 145) {
            int kk = k - 10;
            int rr = kk % 9;
            val = Rs[(size_t)n * 144 + 9 + kk];
            if ((rr & 3) == 0) val -= 1.f;
        } else {
            val = 0.f;
        }
        o[j] = (short)f2bf(val);
    }
    Af[idx] = o;
}

// ---------------- K34: fused MFMA GEMM + LBS blend.
// Block = 1 m-tile (16 samples) x 192 cols (= 64 whole verts). 4 waves x
// 3 col-subtiles x 5 K-steps MFMA -> C into sC[16][194] -> barrier ->
// blend: wave w owns samples 4w..4w+3 (A[n] wave-uniform via readfirstlane
// -> scalar pipe), lane = vert. Writes FINAL verts (no k4a).
__global__ __launch_bounds__(256, 1) void k34_gemm_blend(
    const bf16x8* __restrict__ Af,      // [(N/16)][5][64]
    const bf16x8* __restrict__ Bf,      // [NTB][5][64]
    const float* __restrict__ vtemp,
    const float* __restrict__ Aws,
    const float* __restrict__ weights,
    float* __restrict__ verts,
    int N)
{
    __shared__ float sC[16][194];
    const int tid  = threadIdx.x;
    const int w    = tid >> 6;
    const int lane = tid & 63;
    const int mt   = blockIdx.x;                 // 16 samples
    const int ntb  = blockIdx.y * 12 + w * 3;    // B n-tile base for this wave

    f32x4 acc0 = {0.f,0.f,0.f,0.f};
    f32x4 acc1 = {0.f,0.f,0.f,0.f};
    f32x4 acc2 = {0.f,0.f,0.f,0.f};

    const bf16x8* Ab = Af + (size_t)mt * 5 * 64 + lane;
    const bf16x8* Bb = Bf + lane;

#pragma unroll
    for (int ks = 0; ks < 5; ++ks) {
        bf16x8 a  = Ab[ks * 64];
        bf16x8 b0 = Bb[((size_t)(ntb+0) * 5 + ks) * 64];
        bf16x8 b1 = Bb[((size_t)(ntb+1) * 5 + ks) * 64];
        bf16x8 b2 = Bb[((size_t)(ntb+2) * 5 + ks) * 64];
        acc0 = __builtin_amdgcn_mfma_f32_16x16x32_bf16(a, b0, acc0, 0, 0, 0);
        acc1 = __builtin_amdgcn_mfma_f32_16x16x32_bf16(a, b1, acc1, 0, 0, 0);
        acc2 = __builtin_amdgcn_mfma_f32_16x16x32_bf16(a, b2, acc2, 0, 0, 0);
    }

    // C/D layout: col = lane&15, row = (lane>>4)*4 + r  [m89-verified]
    {
        const int rl = (lane >> 4) * 4;
        const int cl = w * 48 + (lane & 15);
#pragma unroll
        for (int r = 0; r < 4; ++r) {
            sC[rl + r][cl +  0] = acc0[r];
            sC[rl + r][cl + 16] = acc1[r];
            sC[rl + r][cl + 32] = acc2[r];
        }
    }
    __syncthreads();

    // ---- blend phase
    const int vg = blockIdx.y * 64 + lane;      // global vert of this lane
    const bool valid = vg < NV;
    const int cvg = valid ? vg : (NV - 1);

    f32x16 wv = *reinterpret_cast<const f32x16*>(&weights[(size_t)cvg * 16]);
    float vtx = vtemp[cvg*3 + 0];
    float vty = vtemp[cvg*3 + 1];
    float vtz = vtemp[cvg*3 + 2];

#pragma unroll
    for (int it = 0; it < 4; ++it) {
        const int nl = w * 4 + it;
        const int n  = __builtin_amdgcn_readfirstlane(mt * 16 + nl);
        const float* An = Aws + (size_t)n * 192;     // uniform -> s_load path

        float px = sC[nl][lane*3 + 0] + vtx;
        float py = sC[nl][lane*3 + 1] + vty;
        float pz = sC[nl][lane*3 + 2] + vtz;

        float ox = 0.f, oy = 0.f, oz = 0.f;
#define BJF(j_) { \
        float a0=An[(j_)*12+0],  a1=An[(j_)*12+1],  a2 =An[(j_)*12+2],  a3 =An[(j_)*12+3]; \
        float a4=An[(j_)*12+4],  a5=An[(j_)*12+5],  a6 =An[(j_)*12+6],  a7 =An[(j_)*12+7]; \
        float a8=An[(j_)*12+8],  a9=An[(j_)*12+9],  a10=An[(j_)*12+10], a11=An[(j_)*12+11]; \
        float X = fmaf(a0,px, fmaf(a1,py, fmaf(a2,pz, a3))); \
        float Y = fmaf(a4,px, fmaf(a5,py, fmaf(a6,pz, a7))); \
        float Z = fmaf(a8,px, fmaf(a9,py, fmaf(a10,pz, a11))); \
        ox = fmaf(wv[j_], X, ox); oy = fmaf(wv[j_], Y, oy); oz = fmaf(wv[j_], Z, oz); }
        BJF(0)  BJF(1)  BJF(2)  BJF(3)  BJF(4)  BJF(5)  BJF(6)  BJF(7)
        BJF(8)  BJF(9)  BJF(10) BJF(11) BJF(12) BJF(13) BJF(14) BJF(15)
#undef BJF

        if (valid) {
            float* o = verts + (size_t)(mt*16 + nl) * M3 + (size_t)vg * 3;
            o[0] = ox; o[1] = oy; o[2] = oz;
        }
    }
}

// ---------------- K4b: joint regression, fused final sum. Block = 4 samples.
__global__ __launch_bounds__(256, 1) void k4b_joints(
    const float* __restrict__ verts,
    const float* __restrict__ Jreg,
    float* __restrict__ joints,
    int N)
{
    __shared__ float part[4][4][48];
    const int tid = threadIdx.x;
    const int nl  = tid >> 6;            // 0..3 local sample
    const int sub = tid & 63;
    const int j   = sub & 15;
    const int c4  = sub >> 4;            // 0..3
    const int n   = blockIdx.x * 4 + nl;

    int vbeg = c4 * 195;
    int vend = vbeg + 195; if (vend > NV) vend = NV;

    const float* vp = verts + (size_t)n * M3;
    float a0 = 0.f, a1 = 0.f, a2 = 0.f;
#pragma unroll 4
    for (int v = vbeg; v < vend; ++v) {
        float jr = Jreg[(size_t)v * 16 + j];
        float x = vp[v*3 + 0], y = vp[v*3 + 1], z = vp[v*3 + 2];
        a0 = fmaf(jr, x, a0);
        a1 = fmaf(jr, y, a1);
        a2 = fmaf(jr, z, a2);
    }
    part[nl][c4][j*3+0] = a0;
    part[nl][c4][j*3+1] = a1;
    part[nl][c4][j*3+2] = a2;
    __syncthreads();

    if (tid < 192) {
        int nl2 = tid / 48;
        int r   = tid % 48;
        float s = part[nl2][0][r] + part[nl2][1][r] + part[nl2][2][r] + part[nl2][3][r];
        joints[(size_t)(blockIdx.x * 4 + nl2) * 48 + r] = s;
    }
}

extern "C" void kernel_launch(void* const* d_in, const int* in_sizes, int n_in,
                              void* d_out, int out_size, void* d_ws, size_t ws_size,
                              hipStream_t stream)
{
    const float* beta   = (const float*)d_in[0];
    const float* theta  = (const float*)d_in[1];
    const float* vtemp  = (const float*)d_in[2];
    const float* shaped = (const float*)d_in[3];
    const float* Jreg   = (const float*)d_in[4];
    const float* posed  = (const float*)d_in[5];
    const float* wts    = (const float*)d_in[6];
    float* out = (float*)d_out;
    const int N = in_sizes[0] / 10;   // 4096

    float* verts  = out;                            // N*2334
    float* joints = out + (size_t)N * M3;           // N*48
    float* RsOut  = joints + (size_t)N * 48;        // N*144
    float* Aws    = (float*)d_ws;                   // N*192 floats = 3.1 MB
    float*  fbase = Aws + (size_t)N * 192;
    bf16x8* Af    = (bf16x8*)fbase;                           // (N/16)*5*64 *16B
    bf16x8* Bf    = (bf16x8*)(fbase + (size_t)(N/16)*5*64*4); // NTB*5*64 *16B

    const int nA = (N / 16) * 5 * 64;
    const int nB = NTB * 5 * 64;
    const int rodBlocks = (N * NJ) / 256;
    const int KB2 = (N * 5 + 255) / 256;

    k01_prep<<<44 + rodBlocks + (nB + 255)/256, 256, 0, stream>>>(
        shaped, posed, Jreg, vtemp, theta, joints, RsOut, Bf, N);
    k2m<<<KB2 + (nA + 255)/256, 256, 0, stream>>>(
        beta, RsOut, joints, Aws, Af, N);
    k34_gemm_blend<<<dim3(N/16, 13), 256, 0, stream>>>(
        Af, Bf, vtemp, Aws, wts, verts, N);
    k4b_joints<<<N/4, 256, 0, stream>>>(verts, Jreg, joints, N);
}